// Round 6
// baseline (403.779 us; speedup 1.0000x reference)
//
#include <hip/hip_runtime.h>
#include <hip/hip_bf16.h>
#include <stdint.h>

// Problem constants
#define BB   2
#define SS   2048
#define HHH  2048
#define NHH  16
#define HDD  128
#define MTOT 4096   // BB*SS

typedef __bf16 bf16x8 __attribute__((ext_vector_type(8)));
typedef float  f32x4  __attribute__((ext_vector_type(4)));
typedef float  f32x16 __attribute__((ext_vector_type(16)));

#define MFMA16(a, b, c) __builtin_amdgcn_mfma_f32_16x16x32_bf16((a), (b), (c), 0, 0, 0)
#define MFMA32(a, b, c) __builtin_amdgcn_mfma_f32_32x32x16_bf16((a), (b), (c), 0, 0, 0)

__device__ __forceinline__ unsigned short f2bf(float f) {
    union { float f; unsigned u; } v; v.f = f;
    unsigned r = v.u + 0x7FFFu + ((v.u >> 16) & 1u);   // RNE
    return (unsigned short)(r >> 16);
}

__device__ __forceinline__ unsigned packbf(float a, float b) {
    union { __bf16 h[2]; unsigned u; } p;
    p.h[0] = (__bf16)a; p.h[1] = (__bf16)b;
    return p.u;
}

// v_permlane32_swap_b32: a' = [a.lo32, b.lo32], b' = [a.hi32, b.hi32]
__device__ __forceinline__ void pswap(unsigned &a, unsigned &b) {
    asm("v_permlane32_swap_b32 %0, %1" : "+v"(a), "+v"(b));
}

// cross-half (lane ^ 32) pair: returns {own-half view, other-half view}
__device__ __forceinline__ float2 xswap(float x) {
    unsigned a = __builtin_bit_cast(unsigned, x);
    unsigned b;
    asm("v_mov_b32 %0, %1" : "=v"(b) : "v"(a));   // force distinct register
    asm("v_permlane32_swap_b32 %0, %1" : "+v"(a), "+v"(b));
    return make_float2(__builtin_bit_cast(float, a), __builtin_bit_cast(float, b));
}

// async global->LDS, 16B per lane. LDS dest is wave-uniform base + lane*16.
__device__ __forceinline__ void gload16(const void* src, void* lds) {
    __builtin_amdgcn_global_load_lds(
        (__attribute__((address_space(1))) void*)src,
        (__attribute__((address_space(3))) void*)lds,
        16, 0, 0);
}

__device__ __forceinline__ float bflo(unsigned w) {
    return __builtin_bit_cast(float, w << 16);
}
__device__ __forceinline__ float bfhi(unsigned w) {
    return __builtin_bit_cast(float, w & 0xffff0000u);
}

// ---------------- cast f32 -> bf16 (vectorized) ----------------
__global__ void cast_f32_bf16(const float* __restrict__ in,
                              unsigned short* __restrict__ out, int n) {
    int i = (blockIdx.x * blockDim.x + threadIdx.x) * 4;
    int stride = gridDim.x * blockDim.x * 4;
    for (; i < n; i += stride) {
        float4 v = *(const float4*)(in + i);
        ushort4 o;
        o.x = f2bf(v.x); o.y = f2bf(v.y); o.z = f2bf(v.z); o.w = f2bf(v.w);
        *(ushort4*)(out + i) = o;
    }
}

// -------- transpose + cast all 4 weights: W (K x N f32) -> Wt (N x K bf16) --------
__global__ void transpose_cast4(const float* __restrict__ W0, const float* __restrict__ W1,
                                const float* __restrict__ W2, const float* __restrict__ W3,
                                unsigned short* __restrict__ out) {
    const float* in = blockIdx.z == 0 ? W0 : blockIdx.z == 1 ? W1 : blockIdx.z == 2 ? W2 : W3;
    unsigned short* o = out + (size_t)blockIdx.z * ((size_t)HHH * HHH);
    __shared__ float tile[32][33];
    int c0 = blockIdx.x * 32, r0 = blockIdx.y * 32;
    int tx = threadIdx.x, ty = threadIdx.y;   // (32, 8)
    #pragma unroll
    for (int i = 0; i < 32; i += 8)
        tile[ty + i][tx] = in[(size_t)(r0 + ty + i) * HHH + c0 + tx];
    __syncthreads();
    #pragma unroll
    for (int i = 0; i < 32; i += 8)
        o[(size_t)(c0 + ty + i) * HHH + r0 + tx] = f2bf(tile[tx][ty + i]);
}

// ---------------- 8-phase GEMM: C[M,N] = A[M,K] @ Bt[N,K]^T + bias ----------------
// BM=128, BN=256, BK=64. 8 waves (2M x 4N), per-wave 64x64 out, 512 threads.
// Triple-buffered LDS (3 x 48KB): 2-deep prefetch, counted vmcnt(6) at tile end.
template<int MODE>
__global__ __launch_bounds__(512, 2) void gemm8_bf16(
    const unsigned short* __restrict__ A,
    const unsigned short* __restrict__ Bt,
    const float* __restrict__ bias,
    void* __restrict__ Cout,
    int M, int N, int K)
{
    __shared__ __align__(16) unsigned char sm[147456];
    const int tid = threadIdx.x;
    const int wv = tid >> 6, ln = tid & 63;
    const int g = ln >> 4, r = ln & 15;
    const int wr = wv >> 2, wc = wv & 3;

    const int bid = blockIdx.x;
    const int lb = (bid & 7) * 32 + (bid >> 3);
    const int m0 = (lb & 31) * 128;
    const int n0 = (lb >> 5) * 256;

    unsigned srcA[2]; int ldsA[2];
    #pragma unroll
    for (int j = 0; j < 2; ++j) {
        int o = j * 8192 + tid * 16;
        int row = o >> 7;
        int lg = ((o >> 4) & 7) ^ (row & 7);
        srcA[j] = (unsigned)(m0 + row) * K + lg * 8;
        ldsA[j] = o;
    }
    unsigned srcB[4]; int ldsB[4];
    #pragma unroll
    for (int j = 0; j < 4; ++j) {
        int o = j * 8192 + tid * 16;
        int row = o >> 7;
        int lg = ((o >> 4) & 7) ^ (row & 7);
        srcB[j] = (unsigned)(n0 + row) * K + lg * 8;
        ldsB[j] = 16384 + o;
    }

    f32x4 acc[4][4];
    #pragma unroll
    for (int i = 0; i < 4; ++i)
        #pragma unroll
        for (int j = 0; j < 4; ++j)
            acc[i][j] = (f32x4){0.f, 0.f, 0.f, 0.f};

    const int NT = K >> 6;   // 32

    {
        unsigned char* b0 = sm;
        unsigned char* b1 = sm + 49152;
        #pragma unroll
        for (int j = 0; j < 2; ++j) gload16(A + srcA[j], b0 + ldsA[j]);
        #pragma unroll
        for (int j = 0; j < 4; ++j) gload16(Bt + srcB[j], b0 + ldsB[j]);
        #pragma unroll
        for (int j = 0; j < 2; ++j) gload16(A + srcA[j] + 64, b1 + ldsA[j]);
        #pragma unroll
        for (int j = 0; j < 4; ++j) gload16(Bt + srcB[j] + 64, b1 + ldsB[j]);
    }
    asm volatile("s_waitcnt vmcnt(6)" ::: "memory");
    __builtin_amdgcn_s_barrier();

    int csel = 0;
    int psel = 2;
    for (int t = 0; t < NT; ++t) {
        const unsigned char* Ab = sm + csel * 49152;
        const unsigned char* Bb = Ab + 16384;
        unsigned char* Pb = sm + psel * 49152;
        const bool pre = (t + 2 < NT);
        const int ko = (t + 2) * 64;

        bf16x8 af[2][2], bf[2][2];
        #define LDA(mi, ks) (*(const bf16x8*)(Ab + (wr * 64 + (mi) * 16 + r) * 128 + \
                             ((((ks) << 2) + g) ^ ((wr * 64 + (mi) * 16 + r) & 7)) * 16))
        #define LDB(ni, ks) (*(const bf16x8*)(Bb + (wc * 64 + (ni) * 16 + r) * 128 + \
                             ((((ks) << 2) + g) ^ ((wc * 64 + (ni) * 16 + r) & 7)) * 16))

        // ---- phase 0
        af[0][0] = LDA(0, 0); af[0][1] = LDA(0, 1);
        af[1][0] = LDA(1, 0); af[1][1] = LDA(1, 1);
        bf[0][0] = LDB(0, 0); bf[0][1] = LDB(0, 1);
        bf[1][0] = LDB(1, 0); bf[1][1] = LDB(1, 1);
        if (pre) { gload16(Bt + srcB[0] + ko, Pb + ldsB[0]);
                   gload16(Bt + srcB[1] + ko, Pb + ldsB[1]); }
        __builtin_amdgcn_s_barrier();
        asm volatile("s_waitcnt lgkmcnt(0)" ::: "memory");
        __builtin_amdgcn_s_setprio(1);
        #pragma unroll
        for (int mi = 0; mi < 2; ++mi)
            #pragma unroll
            for (int ni = 0; ni < 2; ++ni)
                #pragma unroll
                for (int ks = 0; ks < 2; ++ks)
                    acc[mi][ni] = MFMA16(af[mi][ks], bf[ni][ks], acc[mi][ni]);
        __builtin_amdgcn_s_setprio(0);
        __builtin_amdgcn_s_barrier();

        // ---- phase 1
        bf[0][0] = LDB(2, 0); bf[0][1] = LDB(2, 1);
        bf[1][0] = LDB(3, 0); bf[1][1] = LDB(3, 1);
        if (pre) { gload16(Bt + srcB[2] + ko, Pb + ldsB[2]);
                   gload16(Bt + srcB[3] + ko, Pb + ldsB[3]); }
        __builtin_amdgcn_s_barrier();
        asm volatile("s_waitcnt lgkmcnt(0)" ::: "memory");
        __builtin_amdgcn_s_setprio(1);
        #pragma unroll
        for (int mi = 0; mi < 2; ++mi)
            #pragma unroll
            for (int ni = 0; ni < 2; ++ni)
                #pragma unroll
                for (int ks = 0; ks < 2; ++ks)
                    acc[mi][ni + 2] = MFMA16(af[mi][ks], bf[ni][ks], acc[mi][ni + 2]);
        __builtin_amdgcn_s_setprio(0);
        __builtin_amdgcn_s_barrier();

        // ---- phase 2
        af[0][0] = LDA(2, 0); af[0][1] = LDA(2, 1);
        af[1][0] = LDA(3, 0); af[1][1] = LDA(3, 1);
        if (pre) { gload16(A + srcA[0] + ko, Pb + ldsA[0]);
                   gload16(A + srcA[1] + ko, Pb + ldsA[1]); }
        __builtin_amdgcn_s_barrier();
        asm volatile("s_waitcnt lgkmcnt(0)" ::: "memory");
        __builtin_amdgcn_s_setprio(1);
        #pragma unroll
        for (int mi = 0; mi < 2; ++mi)
            #pragma unroll
            for (int ni = 0; ni < 2; ++ni)
                #pragma unroll
                for (int ks = 0; ks < 2; ++ks)
                    acc[mi + 2][ni + 2] = MFMA16(af[mi][ks], bf[ni][ks], acc[mi + 2][ni + 2]);
        __builtin_amdgcn_s_setprio(0);
        __builtin_amdgcn_s_barrier();

        // ---- phase 3
        bf[0][0] = LDB(0, 0); bf[0][1] = LDB(0, 1);
        bf[1][0] = LDB(1, 0); bf[1][1] = LDB(1, 1);
        __builtin_amdgcn_s_barrier();
        asm volatile("s_waitcnt lgkmcnt(0)" ::: "memory");
        __builtin_amdgcn_s_setprio(1);
        #pragma unroll
        for (int mi = 0; mi < 2; ++mi)
            #pragma unroll
            for (int ni = 0; ni < 2; ++ni)
                #pragma unroll
                for (int ks = 0; ks < 2; ++ks)
                    acc[mi + 2][ni] = MFMA16(af[mi][ks], bf[ni][ks], acc[mi + 2][ni]);
        __builtin_amdgcn_s_setprio(0);
        __builtin_amdgcn_s_barrier();

        if (pre) asm volatile("s_waitcnt vmcnt(6)" ::: "memory");
        else     asm volatile("s_waitcnt vmcnt(0)" ::: "memory");
        __builtin_amdgcn_s_barrier();

        csel = (csel == 2) ? 0 : csel + 1;
        psel = (psel == 2) ? 0 : psel + 1;
        #undef LDA
        #undef LDB
    }

    #pragma unroll
    for (int mt = 0; mt < 4; ++mt) {
        #pragma unroll
        for (int nt = 0; nt < 4; ++nt) {
            int col = n0 + wc * 64 + nt * 16 + r;
            float bvv = bias[col];
            f32x4 a = acc[mt][nt];
            int mrow = m0 + wr * 64 + mt * 16 + g * 4;
            if (MODE == 0) {
                #pragma unroll
                for (int q = 0; q < 4; ++q)
                    ((unsigned short*)Cout)[(size_t)(mrow + q) * N + col] = f2bf(a[q] + bvv);
            } else if (MODE == 2) {
                #pragma unroll
                for (int q = 0; q < 4; ++q)
                    ((float*)Cout)[(size_t)(mrow + q) * N + col] = a[q] + bvv;
            } else {
                int b = mrow >> 11, s0x = mrow & 2047;
                ushort4 o;
                o.x = f2bf(a[0] + bvv); o.y = f2bf(a[1] + bvv);
                o.z = f2bf(a[2] + bvv); o.w = f2bf(a[3] + bvv);
                *(ushort4*)((unsigned short*)Cout + ((size_t)(b * 2048 + col)) * 2048 + s0x) = o;
            }
        }
    }
}

// ---------------- flash attention, KV-split x2, KVBLK=32, 4 blocks/CU ----------------
// Each block: 128 q-rows x 1024 keys (split sp). Partial O (normalized, bf16) + (m,l).
__global__ __launch_bounds__(256, 4) void attn_fwd(
    const unsigned short* __restrict__ Q,
    const unsigned short* __restrict__ K,
    const unsigned short* __restrict__ V,
    const float* __restrict__ mask,
    unsigned short* __restrict__ P0,
    unsigned short* __restrict__ P1,
    float2* __restrict__ ML0,
    float2* __restrict__ ML1)
{
    __shared__ __align__(16) unsigned char sm[32768]; // dbuf: {K[32][128], Vt[128][32]} x2
    const int tid = threadIdx.x, wv = tid >> 6, ln = tid & 63;
    const int hi = ln >> 5, qr = ln & 31;

    // XCD-bijective swizzle (1024 blocks = 8 XCD x 128); XCD owns 4 (b,h) pairs fully.
    const int bid = blockIdx.x;
    const int lb = (bid & 7) * 128 + (bid >> 3);
    const int sp = lb & 1;
    const int qb = (lb >> 1) & 15;
    const int bh = lb >> 5;
    const int h = bh & 15, b = bh >> 4;

    const size_t rowQ0 = (size_t)(b * 2048 + qb * 128 + wv * 32);
    const int kbase = sp * 1024;
    const float SCL2 = 0.08838834764831845f * 1.4426950408889634f; // scale*log2e
    const float L2E  = 1.4426950408889634f;

    // staging precompute: K tile [32][128] (256B rows, 16 granules, ^(row&7));
    //                     Vt tile [128][32] (64B rows, 4 granules, ^(d&3))
    unsigned srcK[2], srcV[2];
    int ldsK[2], ldsV[2];
    #pragma unroll
    for (int i = 0; i < 2; ++i) {
        int ch = wv * 2 + i;
        int o = ch * 1024 + ln * 16;
        { int row = o >> 8; int gl = ((o >> 4) & 15) ^ (row & 7);
          srcK[i] = (unsigned)((b * 2048 + kbase + row) * 2048 + h * 128 + gl * 8);
          ldsK[i] = o; }
        { int d = o >> 6; int gl = ((o >> 4) & 3) ^ (d & 3);
          srcV[i] = (unsigned)((b * 2048 + h * 128 + d) * 2048 + kbase + gl * 8);
          ldsV[i] = 8192 + o; }
    }

    // stage tile 0 into buffer 0
    #pragma unroll
    for (int i = 0; i < 2; ++i) {
        gload16(K + srcK[i], sm + ldsK[i]);
        gload16(V + srcV[i], sm + ldsV[i]);
    }

    // Q fragments (B-operand): col = qr, k = hi*8+j, 8 k-steps of 16
    bf16x8 qf[8];
    #pragma unroll
    for (int ks = 0; ks < 8; ++ks)
        qf[ks] = *(const bf16x8*)(Q + (rowQ0 + qr) * 2048 + h * 128 + ks * 16 + hi * 8);

    f32x16 acc[4];
    #pragma unroll
    for (int i = 0; i < 4; ++i)
        #pragma unroll
        for (int j = 0; j < 16; ++j)
            acc[i][j] = 0.f;
    float mr = -3.0e38f, lr = 0.f;   // per-lane: q-row = qr

    const float* mb = mask + b * 2048 + kbase;
    int cur = 0;
    __syncthreads();   // tile 0 ready

    for (int t = 0; t < 32; ++t) {
        const int kb = t * 32;
        if (t + 1 < 32) {
            unsigned char* dst = sm + (cur ^ 1) * 16384;
            #pragma unroll
            for (int i = 0; i < 2; ++i) {
                gload16(K + srcK[i] + (kb + 32) * 2048, dst + ldsK[i]);
                gload16(V + srcV[i] + (kb + 32), dst + ldsV[i]);
            }
        }
        const unsigned char* Kt = sm + cur * 16384;
        const unsigned char* Vt = Kt + 8192;

        // mask values: key = rg*8 + hi*4 + q4
        f32x4 mk[4];
        #pragma unroll
        for (int rg = 0; rg < 4; ++rg)
            mk[rg] = *(const f32x4*)(mb + kb + rg * 8 + hi * 4);

        // S^T = K Q^T (keys 0..31 on rows, q on cols)
        f32x16 sf;
        #pragma unroll
        for (int j = 0; j < 16; ++j) sf[j] = 0.f;
        __builtin_amdgcn_s_setprio(1);
        #pragma unroll
        for (int ks = 0; ks < 8; ++ks) {
            int s0 = (2 * ks + hi) ^ (qr & 7);
            bf16x8 kf = *(const bf16x8*)(Kt + qr * 256 + s0 * 16);
            sf = MFMA32(kf, qf[ks], sf);
        }
        __builtin_amdgcn_s_setprio(0);

        // scale + mask (log2 domain)
        float sv[16];
        #pragma unroll
        for (int reg = 0; reg < 16; ++reg)
            sv[reg] = sf[reg] * SCL2 + mk[reg >> 2][reg & 3] * L2E;

        // row max: balanced tree over 16 in-lane, then cross-half permlane
        float mx[8];
        #pragma unroll
        for (int j = 0; j < 8; ++j)
            mx[j] = fmaxf(sv[2 * j], sv[2 * j + 1]);
        float m01 = fmaxf(fmaxf(fmaxf(mx[0], mx[1]), fmaxf(mx[2], mx[3])),
                          fmaxf(fmaxf(mx[4], mx[5]), fmaxf(mx[6], mx[7])));
        float2 mp = xswap(m01);
        float mt = fmaxf(mp.x, mp.y);

        // defer-max
        float alpha = 1.f;
        int allskip = __all(mt <= mr + 8.f);
        if (!allskip) {
            float nm = fmaxf(mr, mt);
            alpha = __builtin_amdgcn_exp2f(mr - nm);
            mr = nm;
            #pragma unroll
            for (int dblk = 0; dblk < 4; ++dblk)
                #pragma unroll
                for (int reg = 0; reg < 16; ++reg)
                    acc[dblk][reg] *= alpha;
        }

        // P = exp2(S - m), row sum (4 partials), cross-half permlane
        float s0 = 0.f, s1 = 0.f, s2 = 0.f, s3 = 0.f;
        #pragma unroll
        for (int reg = 0; reg < 16; reg += 4) {
            float p0 = __builtin_amdgcn_exp2f(sv[reg + 0] - mr);
            float p1 = __builtin_amdgcn_exp2f(sv[reg + 1] - mr);
            float p2 = __builtin_amdgcn_exp2f(sv[reg + 2] - mr);
            float p3 = __builtin_amdgcn_exp2f(sv[reg + 3] - mr);
            sv[reg + 0] = p0; sv[reg + 1] = p1;
            sv[reg + 2] = p2; sv[reg + 3] = p3;
            s0 += p0; s1 += p1; s2 += p2; s3 += p3;
        }
        float rsl = (s0 + s1) + (s2 + s3);
        float2 rp = xswap(rsl);
        float rs = rp.x + rp.y;
        lr = lr * alpha + rs;

        // P -> PV B-fragments via permlane32_swap (kb16 in {0,1})
        bf16x8 pfr[2];
        #pragma unroll
        for (int kb16 = 0; kb16 < 2; ++kb16) {
            unsigned W00 = packbf(sv[(2*kb16+0)*4 + 0], sv[(2*kb16+0)*4 + 1]);
            unsigned W01 = packbf(sv[(2*kb16+0)*4 + 2], sv[(2*kb16+0)*4 + 3]);
            unsigned W10 = packbf(sv[(2*kb16+1)*4 + 0], sv[(2*kb16+1)*4 + 1]);
            unsigned W11 = packbf(sv[(2*kb16+1)*4 + 2], sv[(2*kb16+1)*4 + 3]);
            pswap(W00, W10);
            pswap(W01, W11);
            union { unsigned w[4]; bf16x8 v; } u;
            u.w[0] = W00; u.w[1] = W01; u.w[2] = W10; u.w[3] = W11;
            pfr[kb16] = u.v;
        }

        // O^T += V^T P^T
        __builtin_amdgcn_s_setprio(1);
        #pragma unroll
        for (int dblk = 0; dblk < 4; ++dblk) {
            int d = dblk * 32 + qr;
            f32x16 a = acc[dblk];
            #pragma unroll
            for (int kb16 = 0; kb16 < 2; ++kb16) {
                int s = (2 * kb16 + hi) ^ (d & 3);
                bf16x8 vf = *(const bf16x8*)(Vt + d * 64 + s * 16);
                a = MFMA32(vf, pfr[kb16], a);
            }
            acc[dblk] = a;
        }
        __builtin_amdgcn_s_setprio(0);

        __syncthreads();
        cur ^= 1;
    }

    // epilogue: normalized partial O (bf16) + (m,l)
    float linv = 1.f / lr;
    unsigned short* Pp = sp ? P1 : P0;
    unsigned short* orow = Pp + (rowQ0 + qr) * 2048 + h * 128;
    #pragma unroll
    for (int dblk = 0; dblk < 4; ++dblk)
        #pragma unroll
        for (int rg = 0; rg < 4; ++rg) {
            float v0 = acc[dblk][rg * 4 + 0] * linv;
            float v1 = acc[dblk][rg * 4 + 1] * linv;
            float v2 = acc[dblk][rg * 4 + 2] * linv;
            float v3 = acc[dblk][rg * 4 + 3] * linv;
            uint2 o;
            o.x = packbf(v0, v1);
            o.y = packbf(v2, v3);
            *(uint2*)(orow + dblk * 32 + rg * 8 + hi * 4) = o;
        }
    if (hi == 0) {
        float2* ml = sp ? ML1 : ML0;
        ml[(rowQ0 + qr) * 16 + h] = make_float2(mr, lr);
    }
}

// ---------------- combine two KV-split halves ----------------
// O = (w0*l0*O0 + w1*l1*O1) / (w0*l0 + w1*l1), w_s = exp2(m_s - M)
__global__ void attn_combine(const unsigned short* __restrict__ P0,
                             const unsigned short* __restrict__ P1,
                             const float2* __restrict__ ML0,
                             const float2* __restrict__ ML1,
                             unsigned short* __restrict__ O)
{
    int t = blockIdx.x * 256 + threadIdx.x;
    int base = t * 8;                       // 8 bf16 per thread
    int row = base >> 11;
    int h = (base & 2047) >> 7;
    float2 a = ML0[row * 16 + h];
    float2 c = ML1[row * 16 + h];
    float M = fmaxf(a.x, c.x);
    float w0 = __builtin_amdgcn_exp2f(a.x - M) * a.y;
    float w1 = __builtin_amdgcn_exp2f(c.x - M) * c.y;
    float inv = 1.f / (w0 + w1);
    w0 *= inv; w1 *= inv;
    uint4 u0 = *(const uint4*)(P0 + base);
    uint4 u1 = *(const uint4*)(P1 + base);
    uint4 o;
    o.x = packbf(w0 * bflo(u0.x) + w1 * bflo(u1.x), w0 * bfhi(u0.x) + w1 * bfhi(u1.x));
    o.y = packbf(w0 * bflo(u0.y) + w1 * bflo(u1.y), w0 * bfhi(u0.y) + w1 * bfhi(u1.y));
    o.z = packbf(w0 * bflo(u0.z) + w1 * bflo(u1.z), w0 * bfhi(u0.z) + w1 * bfhi(u1.z));
    o.w = packbf(w0 * bflo(u0.w) + w1 * bflo(u1.w), w0 * bfhi(u0.w) + w1 * bfhi(u1.w));
    *(uint4*)(O + base) = o;
}

// ---------------- host launch ----------------
extern "C" void kernel_launch(void* const* d_in, const int* in_sizes, int n_in,
                              void* d_out, int out_size, void* d_ws, size_t ws_size,
                              hipStream_t stream)
{
    (void)in_sizes; (void)n_in; (void)out_size; (void)ws_size;
    const float* x    = (const float*)d_in[0];
    const float* mask = (const float*)d_in[1];
    const float* Wq   = (const float*)d_in[2];
    const float* bq   = (const float*)d_in[3];
    const float* Wk   = (const float*)d_in[4];
    const float* bk   = (const float*)d_in[5];
    const float* Wv   = (const float*)d_in[6];
    const float* bv   = (const float*)d_in[7];
    const float* Wo   = (const float*)d_in[8];
    const float* bo   = (const float*)d_in[9];
    float* out = (float*)d_out;

    char* ws = (char*)d_ws;
    // Region plan (all <= 96 MB):
    //  0..16  xb (bf16 x)           -> reused as Op0 (partial O, split 0) during attn
    // 16..32  Wqt,Wkt               -> reused as Op1 (split 1) during attn
    // 32..40  Wvt                   -> reused as ML0/ML1 after V GEMM
    // 40..48  Wot (live to the end)
    // 48..64  Qb                    -> reused as Ab (combine output) after attn
    // 64..80  Kb   80..96 Vtb
    unsigned short* xb  = (unsigned short*)(ws);
    unsigned short* Wqt = (unsigned short*)(ws + (16u << 20));
    unsigned short* Wkt = (unsigned short*)(ws + (24u << 20));
    unsigned short* Wvt = (unsigned short*)(ws + (32u << 20));
    unsigned short* Wot = (unsigned short*)(ws + (40u << 20));
    unsigned short* Qb  = (unsigned short*)(ws + (48u << 20));
    unsigned short* Kb  = (unsigned short*)(ws + (64u << 20));
    unsigned short* Vtb = (unsigned short*)(ws + (80u << 20));
    unsigned short* Op0 = (unsigned short*)(ws);
    unsigned short* Op1 = (unsigned short*)(ws + (16u << 20));
    float2*         ML0 = (float2*)(ws + (32u << 20));
    float2*         ML1 = (float2*)(ws + (36u << 20));
    unsigned short* Ab  = (unsigned short*)(ws + (48u << 20));

    cast_f32_bf16<<<2048, 256, 0, stream>>>(x, xb, MTOT * HHH);
    transpose_cast4<<<dim3(64, 64, 4), dim3(32, 8), 0, stream>>>(Wq, Wk, Wv, Wo, Wqt);

    gemm8_bf16<0><<<256, 512, 0, stream>>>(xb, Wqt, bq, Qb,  MTOT, HHH, HHH);
    gemm8_bf16<0><<<256, 512, 0, stream>>>(xb, Wkt, bk, Kb,  MTOT, HHH, HHH);
    gemm8_bf16<1><<<256, 512, 0, stream>>>(xb, Wvt, bv, Vtb, MTOT, HHH, HHH);

    attn_fwd<<<1024, 256, 0, stream>>>(Qb, Kb, Vtb, mask, Op0, Op1, ML0, ML1);
    attn_combine<<<(MTOT * HHH) / (256 * 8), 256, 0, stream>>>(Op0, Op1, ML0, ML1, Ab);

    gemm8_bf16<2><<<256, 512, 0, stream>>>(Ab, Wot, bo, out, MTOT, HHH, HHH);
}

// Round 7
// 402.549 us; speedup vs baseline: 1.0031x; 1.0031x over previous
//
#include <hip/hip_runtime.h>
#include <hip/hip_bf16.h>
#include <stdint.h>

// Problem constants
#define BB   2
#define SS   2048
#define HHH  2048
#define NHH  16
#define HDD  128
#define MTOT 4096   // BB*SS

typedef __bf16 bf16x8 __attribute__((ext_vector_type(8)));
typedef float  f32x4  __attribute__((ext_vector_type(4)));
typedef float  f32x16 __attribute__((ext_vector_type(16)));

#define MFMA16(a, b, c) __builtin_amdgcn_mfma_f32_16x16x32_bf16((a), (b), (c), 0, 0, 0)
#define MFMA32(a, b, c) __builtin_amdgcn_mfma_f32_32x32x16_bf16((a), (b), (c), 0, 0, 0)

__device__ __forceinline__ unsigned short f2bf(float f) {
    union { float f; unsigned u; } v; v.f = f;
    unsigned r = v.u + 0x7FFFu + ((v.u >> 16) & 1u);   // RNE
    return (unsigned short)(r >> 16);
}

__device__ __forceinline__ unsigned packbf(float a, float b) {
    union { __bf16 h[2]; unsigned u; } p;
    p.h[0] = (__bf16)a; p.h[1] = (__bf16)b;
    return p.u;
}

// v_permlane32_swap_b32: a' = [a.lo32, b.lo32], b' = [a.hi32, b.hi32]
__device__ __forceinline__ void pswap(unsigned &a, unsigned &b) {
    asm("v_permlane32_swap_b32 %0, %1" : "+v"(a), "+v"(b));
}

// cross-half (lane ^ 32) pair: returns {own-half view, other-half view}
__device__ __forceinline__ float2 xswap(float x) {
    unsigned a = __builtin_bit_cast(unsigned, x);
    unsigned b;
    asm("v_mov_b32 %0, %1" : "=v"(b) : "v"(a));   // force distinct register
    asm("v_permlane32_swap_b32 %0, %1" : "+v"(a), "+v"(b));
    return make_float2(__builtin_bit_cast(float, a), __builtin_bit_cast(float, b));
}

// async global->LDS, 16B per lane. LDS dest is wave-uniform base + lane*16.
__device__ __forceinline__ void gload16(const void* src, void* lds) {
    __builtin_amdgcn_global_load_lds(
        (__attribute__((address_space(1))) void*)src,
        (__attribute__((address_space(3))) void*)lds,
        16, 0, 0);
}

__device__ __forceinline__ float bflo(unsigned w) {
    return __builtin_bit_cast(float, w << 16);
}
__device__ __forceinline__ float bfhi(unsigned w) {
    return __builtin_bit_cast(float, w & 0xffff0000u);
}

// ---------------- cast f32 -> bf16 (vectorized) ----------------
__global__ void cast_f32_bf16(const float* __restrict__ in,
                              unsigned short* __restrict__ out, int n) {
    int i = (blockIdx.x * blockDim.x + threadIdx.x) * 4;
    int stride = gridDim.x * blockDim.x * 4;
    for (; i < n; i += stride) {
        float4 v = *(const float4*)(in + i);
        ushort4 o;
        o.x = f2bf(v.x); o.y = f2bf(v.y); o.z = f2bf(v.z); o.w = f2bf(v.w);
        *(ushort4*)(out + i) = o;
    }
}

// -------- transpose + cast all 4 weights: W (K x N f32) -> Wt (N x K bf16) --------
__global__ void transpose_cast4(const float* __restrict__ W0, const float* __restrict__ W1,
                                const float* __restrict__ W2, const float* __restrict__ W3,
                                unsigned short* __restrict__ out) {
    const float* in = blockIdx.z == 0 ? W0 : blockIdx.z == 1 ? W1 : blockIdx.z == 2 ? W2 : W3;
    unsigned short* o = out + (size_t)blockIdx.z * ((size_t)HHH * HHH);
    __shared__ float tile[32][33];
    int c0 = blockIdx.x * 32, r0 = blockIdx.y * 32;
    int tx = threadIdx.x, ty = threadIdx.y;   // (32, 8)
    #pragma unroll
    for (int i = 0; i < 32; i += 8)
        tile[ty + i][tx] = in[(size_t)(r0 + ty + i) * HHH + c0 + tx];
    __syncthreads();
    #pragma unroll
    for (int i = 0; i < 32; i += 8)
        o[(size_t)(c0 + ty + i) * HHH + r0 + tx] = f2bf(tile[tx][ty + i]);
}

// ---------------- 8-phase GEMM: C[M,N] = A[M,K] @ Bt[N,K]^T + bias ----------------
// BM=128, BN=256, BK=64. 8 waves (2M x 4N), per-wave 64x64 out, 512 threads.
// Triple-buffered LDS (3 x 48KB): 2-deep prefetch, counted vmcnt(6) at tile end.
template<int MODE>
__global__ __launch_bounds__(512, 2) void gemm8_bf16(
    const unsigned short* __restrict__ A,
    const unsigned short* __restrict__ Bt,
    const float* __restrict__ bias,
    void* __restrict__ Cout,
    int M, int N, int K)
{
    __shared__ __align__(16) unsigned char sm[147456];
    const int tid = threadIdx.x;
    const int wv = tid >> 6, ln = tid & 63;
    const int g = ln >> 4, r = ln & 15;
    const int wr = wv >> 2, wc = wv & 3;

    const int bid = blockIdx.x;
    const int lb = (bid & 7) * 32 + (bid >> 3);
    const int m0 = (lb & 31) * 128;
    const int n0 = (lb >> 5) * 256;

    unsigned srcA[2]; int ldsA[2];
    #pragma unroll
    for (int j = 0; j < 2; ++j) {
        int o = j * 8192 + tid * 16;
        int row = o >> 7;
        int lg = ((o >> 4) & 7) ^ (row & 7);
        srcA[j] = (unsigned)(m0 + row) * K + lg * 8;
        ldsA[j] = o;
    }
    unsigned srcB[4]; int ldsB[4];
    #pragma unroll
    for (int j = 0; j < 4; ++j) {
        int o = j * 8192 + tid * 16;
        int row = o >> 7;
        int lg = ((o >> 4) & 7) ^ (row & 7);
        srcB[j] = (unsigned)(n0 + row) * K + lg * 8;
        ldsB[j] = 16384 + o;
    }

    f32x4 acc[4][4];
    #pragma unroll
    for (int i = 0; i < 4; ++i)
        #pragma unroll
        for (int j = 0; j < 4; ++j)
            acc[i][j] = (f32x4){0.f, 0.f, 0.f, 0.f};

    const int NT = K >> 6;   // 32

    {
        unsigned char* b0 = sm;
        unsigned char* b1 = sm + 49152;
        #pragma unroll
        for (int j = 0; j < 2; ++j) gload16(A + srcA[j], b0 + ldsA[j]);
        #pragma unroll
        for (int j = 0; j < 4; ++j) gload16(Bt + srcB[j], b0 + ldsB[j]);
        #pragma unroll
        for (int j = 0; j < 2; ++j) gload16(A + srcA[j] + 64, b1 + ldsA[j]);
        #pragma unroll
        for (int j = 0; j < 4; ++j) gload16(Bt + srcB[j] + 64, b1 + ldsB[j]);
    }
    asm volatile("s_waitcnt vmcnt(6)" ::: "memory");
    __builtin_amdgcn_s_barrier();

    int csel = 0;
    int psel = 2;
    for (int t = 0; t < NT; ++t) {
        const unsigned char* Ab = sm + csel * 49152;
        const unsigned char* Bb = Ab + 16384;
        unsigned char* Pb = sm + psel * 49152;
        const bool pre = (t + 2 < NT);
        const int ko = (t + 2) * 64;

        bf16x8 af[2][2], bf[2][2];
        #define LDA(mi, ks) (*(const bf16x8*)(Ab + (wr * 64 + (mi) * 16 + r) * 128 + \
                             ((((ks) << 2) + g) ^ ((wr * 64 + (mi) * 16 + r) & 7)) * 16))
        #define LDB(ni, ks) (*(const bf16x8*)(Bb + (wc * 64 + (ni) * 16 + r) * 128 + \
                             ((((ks) << 2) + g) ^ ((wc * 64 + (ni) * 16 + r) & 7)) * 16))

        // ---- phase 0
        af[0][0] = LDA(0, 0); af[0][1] = LDA(0, 1);
        af[1][0] = LDA(1, 0); af[1][1] = LDA(1, 1);
        bf[0][0] = LDB(0, 0); bf[0][1] = LDB(0, 1);
        bf[1][0] = LDB(1, 0); bf[1][1] = LDB(1, 1);
        if (pre) { gload16(Bt + srcB[0] + ko, Pb + ldsB[0]);
                   gload16(Bt + srcB[1] + ko, Pb + ldsB[1]); }
        __builtin_amdgcn_s_barrier();
        asm volatile("s_waitcnt lgkmcnt(0)" ::: "memory");
        __builtin_amdgcn_s_setprio(1);
        #pragma unroll
        for (int mi = 0; mi < 2; ++mi)
            #pragma unroll
            for (int ni = 0; ni < 2; ++ni)
                #pragma unroll
                for (int ks = 0; ks < 2; ++ks)
                    acc[mi][ni] = MFMA16(af[mi][ks], bf[ni][ks], acc[mi][ni]);
        __builtin_amdgcn_s_setprio(0);
        __builtin_amdgcn_s_barrier();

        // ---- phase 1
        bf[0][0] = LDB(2, 0); bf[0][1] = LDB(2, 1);
        bf[1][0] = LDB(3, 0); bf[1][1] = LDB(3, 1);
        if (pre) { gload16(Bt + srcB[2] + ko, Pb + ldsB[2]);
                   gload16(Bt + srcB[3] + ko, Pb + ldsB[3]); }
        __builtin_amdgcn_s_barrier();
        asm volatile("s_waitcnt lgkmcnt(0)" ::: "memory");
        __builtin_amdgcn_s_setprio(1);
        #pragma unroll
        for (int mi = 0; mi < 2; ++mi)
            #pragma unroll
            for (int ni = 0; ni < 2; ++ni)
                #pragma unroll
                for (int ks = 0; ks < 2; ++ks)
                    acc[mi][ni + 2] = MFMA16(af[mi][ks], bf[ni][ks], acc[mi][ni + 2]);
        __builtin_amdgcn_s_setprio(0);
        __builtin_amdgcn_s_barrier();

        // ---- phase 2
        af[0][0] = LDA(2, 0); af[0][1] = LDA(2, 1);
        af[1][0] = LDA(3, 0); af[1][1] = LDA(3, 1);
        if (pre) { gload16(A + srcA[0] + ko, Pb + ldsA[0]);
                   gload16(A + srcA[1] + ko, Pb + ldsA[1]); }
        __builtin_amdgcn_s_barrier();
        asm volatile("s_waitcnt lgkmcnt(0)" ::: "memory");
        __builtin_amdgcn_s_setprio(1);
        #pragma unroll
        for (int mi = 0; mi < 2; ++mi)
            #pragma unroll
            for (int ni = 0; ni < 2; ++ni)
                #pragma unroll
                for (int ks = 0; ks < 2; ++ks)
                    acc[mi + 2][ni + 2] = MFMA16(af[mi][ks], bf[ni][ks], acc[mi + 2][ni + 2]);
        __builtin_amdgcn_s_setprio(0);
        __builtin_amdgcn_s_barrier();

        // ---- phase 3
        bf[0][0] = LDB(0, 0); bf[0][1] = LDB(0, 1);
        bf[1][0] = LDB(1, 0); bf[1][1] = LDB(1, 1);
        __builtin_amdgcn_s_barrier();
        asm volatile("s_waitcnt lgkmcnt(0)" ::: "memory");
        __builtin_amdgcn_s_setprio(1);
        #pragma unroll
        for (int mi = 0; mi < 2; ++mi)
            #pragma unroll
            for (int ni = 0; ni < 2; ++ni)
                #pragma unroll
                for (int ks = 0; ks < 2; ++ks)
                    acc[mi + 2][ni] = MFMA16(af[mi][ks], bf[ni][ks], acc[mi + 2][ni]);
        __builtin_amdgcn_s_setprio(0);
        __builtin_amdgcn_s_barrier();

        if (pre) asm volatile("s_waitcnt vmcnt(6)" ::: "memory");
        else     asm volatile("s_waitcnt vmcnt(0)" ::: "memory");
        __builtin_amdgcn_s_barrier();

        csel = (csel == 2) ? 0 : csel + 1;
        psel = (psel == 2) ? 0 : psel + 1;
        #undef LDA
        #undef LDB
    }

    #pragma unroll
    for (int mt = 0; mt < 4; ++mt) {
        #pragma unroll
        for (int nt = 0; nt < 4; ++nt) {
            int col = n0 + wc * 64 + nt * 16 + r;
            float bvv = bias[col];
            f32x4 a = acc[mt][nt];
            int mrow = m0 + wr * 64 + mt * 16 + g * 4;
            if (MODE == 0) {
                #pragma unroll
                for (int q = 0; q < 4; ++q)
                    ((unsigned short*)Cout)[(size_t)(mrow + q) * N + col] = f2bf(a[q] + bvv);
            } else if (MODE == 2) {
                #pragma unroll
                for (int q = 0; q < 4; ++q)
                    ((float*)Cout)[(size_t)(mrow + q) * N + col] = a[q] + bvv;
            } else {
                int b = mrow >> 11, s0x = mrow & 2047;
                ushort4 o;
                o.x = f2bf(a[0] + bvv); o.y = f2bf(a[1] + bvv);
                o.z = f2bf(a[2] + bvv); o.w = f2bf(a[3] + bvv);
                *(ushort4*)((unsigned short*)Cout + ((size_t)(b * 2048 + col)) * 2048 + s0x) = o;
            }
        }
    }
}

// ---------------- flash attention, interleaved KV-split x2, KVBLK=32 ----------------
// Split sp processes 32-key tiles at kb = t*64 + sp*32: both splits stream the SAME
// K/V region in lockstep -> L2 reuse across all 32 blocks of a head (round-6 fix).
__global__ __launch_bounds__(256, 4) void attn_fwd(
    const unsigned short* __restrict__ Q,
    const unsigned short* __restrict__ K,
    const unsigned short* __restrict__ V,
    const float* __restrict__ mask,
    unsigned short* __restrict__ P0,
    unsigned short* __restrict__ P1,
    float2* __restrict__ ML0,
    float2* __restrict__ ML1)
{
    __shared__ __align__(16) unsigned char sm[32768]; // dbuf: {K[32][128], Vt[128][32]} x2
    const int tid = threadIdx.x, wv = tid >> 6, ln = tid & 63;
    const int hi = ln >> 5, qr = ln & 31;

    // XCD-bijective swizzle (1024 blocks = 8 XCD x 128); XCD owns 4 (b,h) pairs fully.
    const int bid = blockIdx.x;
    const int lb = (bid & 7) * 128 + (bid >> 3);
    const int sp = lb & 1;
    const int qb = (lb >> 1) & 15;
    const int bh = lb >> 5;
    const int h = bh & 15, b = bh >> 4;

    const size_t rowQ0 = (size_t)(b * 2048 + qb * 128 + wv * 32);
    const float SCL2 = 0.08838834764831845f * 1.4426950408889634f; // scale*log2e
    const float L2E  = 1.4426950408889634f;

    // staging precompute: K tile [32][128] (256B rows, 16 granules, ^(row&7));
    //                     Vt tile [128][32] (64B rows, 4 granules, ^((d>>1)&3))
    // Base at this split's first tile: keys sp*32 .. sp*32+31.
    unsigned srcK[2], srcV[2];
    int ldsK[2], ldsV[2];
    #pragma unroll
    for (int i = 0; i < 2; ++i) {
        int ch = wv * 2 + i;
        int o = ch * 1024 + ln * 16;
        { int row = o >> 8; int gl = ((o >> 4) & 15) ^ (row & 7);
          srcK[i] = (unsigned)((b * 2048 + sp * 32 + row) * 2048 + h * 128 + gl * 8);
          ldsK[i] = o; }
        { int d = o >> 6; int gl = ((o >> 4) & 3) ^ ((d >> 1) & 3);
          srcV[i] = (unsigned)((b * 2048 + h * 128 + d) * 2048 + sp * 32 + gl * 8);
          ldsV[i] = 8192 + o; }
    }

    // stage tile 0 into buffer 0
    #pragma unroll
    for (int i = 0; i < 2; ++i) {
        gload16(K + srcK[i], sm + ldsK[i]);
        gload16(V + srcV[i], sm + ldsV[i]);
    }

    // Q fragments (B-operand): col = qr, k = hi*8+j, 8 k-steps of 16
    bf16x8 qf[8];
    #pragma unroll
    for (int ks = 0; ks < 8; ++ks)
        qf[ks] = *(const bf16x8*)(Q + (rowQ0 + qr) * 2048 + h * 128 + ks * 16 + hi * 8);

    f32x16 acc[4];
    #pragma unroll
    for (int i = 0; i < 4; ++i)
        #pragma unroll
        for (int j = 0; j < 16; ++j)
            acc[i][j] = 0.f;
    float mr = -3.0e38f, lr = 0.f;   // per-lane: q-row = qr

    const float* mb = mask + b * 2048 + sp * 32;
    int cur = 0;
    __syncthreads();   // tile 0 ready

    for (int t = 0; t < 32; ++t) {
        const int ko = t * 64;   // element offset from this split's base (64 keys/step)
        if (t + 1 < 32) {
            unsigned char* dst = sm + (cur ^ 1) * 16384;
            #pragma unroll
            for (int i = 0; i < 2; ++i) {
                gload16(K + srcK[i] + (unsigned)(ko + 64) * 2048, dst + ldsK[i]);
                gload16(V + srcV[i] + (ko + 64), dst + ldsV[i]);
            }
        }
        const unsigned char* Kt = sm + cur * 16384;
        const unsigned char* Vt = Kt + 8192;

        // mask values: key = base + ko + rg*8 + hi*4 + q4
        f32x4 mk[4];
        #pragma unroll
        for (int rg = 0; rg < 4; ++rg)
            mk[rg] = *(const f32x4*)(mb + ko + rg * 8 + hi * 4);

        // S^T = K Q^T (keys 0..31 on rows, q on cols)
        f32x16 sf;
        #pragma unroll
        for (int j = 0; j < 16; ++j) sf[j] = 0.f;
        __builtin_amdgcn_s_setprio(1);
        #pragma unroll
        for (int ks = 0; ks < 8; ++ks) {
            int s0 = (2 * ks + hi) ^ (qr & 7);
            bf16x8 kf = *(const bf16x8*)(Kt + qr * 256 + s0 * 16);
            sf = MFMA32(kf, qf[ks], sf);
        }
        __builtin_amdgcn_s_setprio(0);

        // scale + mask (log2 domain)
        float sv[16];
        #pragma unroll
        for (int reg = 0; reg < 16; ++reg)
            sv[reg] = sf[reg] * SCL2 + mk[reg >> 2][reg & 3] * L2E;

        // row max: balanced tree over 16 in-lane, then cross-half permlane
        float mx[8];
        #pragma unroll
        for (int j = 0; j < 8; ++j)
            mx[j] = fmaxf(sv[2 * j], sv[2 * j + 1]);
        float m01 = fmaxf(fmaxf(fmaxf(mx[0], mx[1]), fmaxf(mx[2], mx[3])),
                          fmaxf(fmaxf(mx[4], mx[5]), fmaxf(mx[6], mx[7])));
        float2 mp = xswap(m01);
        float mt = fmaxf(mp.x, mp.y);

        // defer-max
        float alpha = 1.f;
        int allskip = __all(mt <= mr + 8.f);
        if (!allskip) {
            float nm = fmaxf(mr, mt);
            alpha = __builtin_amdgcn_exp2f(mr - nm);
            mr = nm;
            #pragma unroll
            for (int dblk = 0; dblk < 4; ++dblk)
                #pragma unroll
                for (int reg = 0; reg < 16; ++reg)
                    acc[dblk][reg] *= alpha;
        }

        // P = exp2(S - m), row sum (4 partials), cross-half permlane
        float s0 = 0.f, s1 = 0.f, s2 = 0.f, s3 = 0.f;
        #pragma unroll
        for (int reg = 0; reg < 16; reg += 4) {
            float p0 = __builtin_amdgcn_exp2f(sv[reg + 0] - mr);
            float p1 = __builtin_amdgcn_exp2f(sv[reg + 1] - mr);
            float p2 = __builtin_amdgcn_exp2f(sv[reg + 2] - mr);
            float p3 = __builtin_amdgcn_exp2f(sv[reg + 3] - mr);
            sv[reg + 0] = p0; sv[reg + 1] = p1;
            sv[reg + 2] = p2; sv[reg + 3] = p3;
            s0 += p0; s1 += p1; s2 += p2; s3 += p3;
        }
        float rsl = (s0 + s1) + (s2 + s3);
        float2 rp = xswap(rsl);
        float rs = rp.x + rp.y;
        lr = lr * alpha + rs;

        // P -> PV B-fragments via permlane32_swap (kb16 in {0,1})
        bf16x8 pfr[2];
        #pragma unroll
        for (int kb16 = 0; kb16 < 2; ++kb16) {
            unsigned W00 = packbf(sv[(2*kb16+0)*4 + 0], sv[(2*kb16+0)*4 + 1]);
            unsigned W01 = packbf(sv[(2*kb16+0)*4 + 2], sv[(2*kb16+0)*4 + 3]);
            unsigned W10 = packbf(sv[(2*kb16+1)*4 + 0], sv[(2*kb16+1)*4 + 1]);
            unsigned W11 = packbf(sv[(2*kb16+1)*4 + 2], sv[(2*kb16+1)*4 + 3]);
            pswap(W00, W10);
            pswap(W01, W11);
            union { unsigned w[4]; bf16x8 v; } u;
            u.w[0] = W00; u.w[1] = W01; u.w[2] = W10; u.w[3] = W11;
            pfr[kb16] = u.v;
        }

        // O^T += V^T P^T
        __builtin_amdgcn_s_setprio(1);
        #pragma unroll
        for (int dblk = 0; dblk < 4; ++dblk) {
            int d = dblk * 32 + qr;
            f32x16 a = acc[dblk];
            #pragma unroll
            for (int kb16 = 0; kb16 < 2; ++kb16) {
                int s = (2 * kb16 + hi) ^ ((d >> 1) & 3);
                bf16x8 vf = *(const bf16x8*)(Vt + d * 64 + s * 16);
                a = MFMA32(vf, pfr[kb16], a);
            }
            acc[dblk] = a;
        }
        __builtin_amdgcn_s_setprio(0);

        __syncthreads();
        cur ^= 1;
    }

    // epilogue: normalized partial O (bf16) + (m,l)
    float linv = 1.f / lr;
    unsigned short* Pp = sp ? P1 : P0;
    unsigned short* orow = Pp + (rowQ0 + qr) * 2048 + h * 128;
    #pragma unroll
    for (int dblk = 0; dblk < 4; ++dblk)
        #pragma unroll
        for (int rg = 0; rg < 4; ++rg) {
            float v0 = acc[dblk][rg * 4 + 0] * linv;
            float v1 = acc[dblk][rg * 4 + 1] * linv;
            float v2 = acc[dblk][rg * 4 + 2] * linv;
            float v3 = acc[dblk][rg * 4 + 3] * linv;
            uint2 o;
            o.x = packbf(v0, v1);
            o.y = packbf(v2, v3);
            *(uint2*)(orow + dblk * 32 + rg * 8 + hi * 4) = o;
        }
    if (hi == 0) {
        float2* ml = sp ? ML1 : ML0;
        ml[(rowQ0 + qr) * 16 + h] = make_float2(mr, lr);
    }
}

// ---------------- combine two KV-split halves ----------------
// O = (w0*l0*O0 + w1*l1*O1) / (w0*l0 + w1*l1), w_s = exp2(m_s - M)
__global__ void attn_combine(const unsigned short* __restrict__ P0,
                             const unsigned short* __restrict__ P1,
                             const float2* __restrict__ ML0,
                             const float2* __restrict__ ML1,
                             unsigned short* __restrict__ O)
{
    int t = blockIdx.x * 256 + threadIdx.x;
    int base = t * 8;                       // 8 bf16 per thread
    int row = base >> 11;
    int h = (base & 2047) >> 7;
    float2 a = ML0[row * 16 + h];
    float2 c = ML1[row * 16 + h];
    float M = fmaxf(a.x, c.x);
    float w0 = __builtin_amdgcn_exp2f(a.x - M) * a.y;
    float w1 = __builtin_amdgcn_exp2f(c.x - M) * c.y;
    float inv = 1.f / (w0 + w1);
    w0 *= inv; w1 *= inv;
    uint4 u0 = *(const uint4*)(P0 + base);
    uint4 u1 = *(const uint4*)(P1 + base);
    uint4 o;
    o.x = packbf(w0 * bflo(u0.x) + w1 * bflo(u1.x), w0 * bfhi(u0.x) + w1 * bfhi(u1.x));
    o.y = packbf(w0 * bflo(u0.y) + w1 * bflo(u1.y), w0 * bfhi(u0.y) + w1 * bfhi(u1.y));
    o.z = packbf(w0 * bflo(u0.z) + w1 * bflo(u1.z), w0 * bfhi(u0.z) + w1 * bfhi(u1.z));
    o.w = packbf(w0 * bflo(u0.w) + w1 * bflo(u1.w), w0 * bfhi(u0.w) + w1 * bfhi(u1.w));
    *(uint4*)(O + base) = o;
}

// ---------------- host launch ----------------
extern "C" void kernel_launch(void* const* d_in, const int* in_sizes, int n_in,
                              void* d_out, int out_size, void* d_ws, size_t ws_size,
                              hipStream_t stream)
{
    (void)in_sizes; (void)n_in; (void)out_size; (void)ws_size;
    const float* x    = (const float*)d_in[0];
    const float* mask = (const float*)d_in[1];
    const float* Wq   = (const float*)d_in[2];
    const float* bq   = (const float*)d_in[3];
    const float* Wk   = (const float*)d_in[4];
    const float* bk   = (const float*)d_in[5];
    const float* Wv   = (const float*)d_in[6];
    const float* bv   = (const float*)d_in[7];
    const float* Wo   = (const float*)d_in[8];
    const float* bo   = (const float*)d_in[9];
    float* out = (float*)d_out;

    char* ws = (char*)d_ws;
    // Region plan (all <= 96 MB):
    //  0..16  xb   -> reused as Op0 after GEMMs
    // 16..32  Wqt,Wkt -> reused as Op1
    // 32..40  Wvt  -> reused as ML0/ML1
    // 40..48  Wot (live to the end)
    // 48..64  Qb   -> reused as Ab after attn
    // 64..80  Kb   80..96 Vtb
    unsigned short* xb  = (unsigned short*)(ws);
    unsigned short* Wqt = (unsigned short*)(ws + (16u << 20));
    unsigned short* Wkt = (unsigned short*)(ws + (24u << 20));
    unsigned short* Wvt = (unsigned short*)(ws + (32u << 20));
    unsigned short* Wot = (unsigned short*)(ws + (40u << 20));
    unsigned short* Qb  = (unsigned short*)(ws + (48u << 20));
    unsigned short* Kb  = (unsigned short*)(ws + (64u << 20));
    unsigned short* Vtb = (unsigned short*)(ws + (80u << 20));
    unsigned short* Op0 = (unsigned short*)(ws);
    unsigned short* Op1 = (unsigned short*)(ws + (16u << 20));
    float2*         ML0 = (float2*)(ws + (32u << 20));
    float2*         ML1 = (float2*)(ws + (36u << 20));
    unsigned short* Ab  = (unsigned short*)(ws + (48u << 20));

    cast_f32_bf16<<<2048, 256, 0, stream>>>(x, xb, MTOT * HHH);
    transpose_cast4<<<dim3(64, 64, 4), dim3(32, 8), 0, stream>>>(Wq, Wk, Wv, Wo, Wqt);

    gemm8_bf16<0><<<256, 512, 0, stream>>>(xb, Wqt, bq, Qb,  MTOT, HHH, HHH);
    gemm8_bf16<0><<<256, 512, 0, stream>>>(xb, Wkt, bk, Kb,  MTOT, HHH, HHH);
    gemm8_bf16<1><<<256, 512, 0, stream>>>(xb, Wvt, bv, Vtb, MTOT, HHH, HHH);

    attn_fwd<<<1024, 256, 0, stream>>>(Qb, Kb, Vtb, mask, Op0, Op1, ML0, ML1);
    attn_combine<<<(MTOT * HHH) / (256 * 8), 256, 0, stream>>>(Op0, Op1, ML0, ML1, Ab);

    gemm8_bf16<2><<<256, 512, 0, stream>>>(Ab, Wot, bo, out, MTOT, HHH, HHH);
}

// Round 8
// 291.559 us; speedup vs baseline: 1.3849x; 1.3807x over previous
//
#include <hip/hip_runtime.h>
#include <hip/hip_bf16.h>
#include <stdint.h>

// Problem constants
#define BB   2
#define SS   2048
#define HHH  2048
#define NHH  16
#define HDD  128
#define MTOT 4096   // BB*SS

typedef __bf16 bf16x8 __attribute__((ext_vector_type(8)));
typedef float  f32x4  __attribute__((ext_vector_type(4)));
typedef float  f32x16 __attribute__((ext_vector_type(16)));

#define MFMA16(a, b, c) __builtin_amdgcn_mfma_f32_16x16x32_bf16((a), (b), (c), 0, 0, 0)
#define MFMA32(a, b, c) __builtin_amdgcn_mfma_f32_32x32x16_bf16((a), (b), (c), 0, 0, 0)

__device__ __forceinline__ unsigned short f2bf(float f) {
    union { float f; unsigned u; } v; v.f = f;
    unsigned r = v.u + 0x7FFFu + ((v.u >> 16) & 1u);   // RNE
    return (unsigned short)(r >> 16);
}

__device__ __forceinline__ unsigned packbf(float a, float b) {
    union { __bf16 h[2]; unsigned u; } p;
    p.h[0] = (__bf16)a; p.h[1] = (__bf16)b;
    return p.u;
}

// v_permlane32_swap_b32: a' = [a.lo32, b.lo32], b' = [a.hi32, b.hi32]
__device__ __forceinline__ void pswap(unsigned &a, unsigned &b) {
    asm("v_permlane32_swap_b32 %0, %1" : "+v"(a), "+v"(b));
}

// cross-half (lane ^ 32) pair: returns {own-half view, other-half view}
__device__ __forceinline__ float2 xswap(float x) {
    unsigned a = __builtin_bit_cast(unsigned, x);
    unsigned b;
    asm("v_mov_b32 %0, %1" : "=v"(b) : "v"(a));   // force distinct register
    asm("v_permlane32_swap_b32 %0, %1" : "+v"(a), "+v"(b));
    return make_float2(__builtin_bit_cast(float, a), __builtin_bit_cast(float, b));
}

// async global->LDS, 16B per lane. LDS dest is wave-uniform base + lane*16.
__device__ __forceinline__ void gload16(const void* src, void* lds) {
    __builtin_amdgcn_global_load_lds(
        (__attribute__((address_space(1))) void*)src,
        (__attribute__((address_space(3))) void*)lds,
        16, 0, 0);
}

// ---------------- cast f32 -> bf16 (vectorized) ----------------
__global__ void cast_f32_bf16(const float* __restrict__ in,
                              unsigned short* __restrict__ out, int n) {
    int i = (blockIdx.x * blockDim.x + threadIdx.x) * 4;
    int stride = gridDim.x * blockDim.x * 4;
    for (; i < n; i += stride) {
        float4 v = *(const float4*)(in + i);
        ushort4 o;
        o.x = f2bf(v.x); o.y = f2bf(v.y); o.z = f2bf(v.z); o.w = f2bf(v.w);
        *(ushort4*)(out + i) = o;
    }
}

// ---------------- pre-scale mask by log2(e) ----------------
__global__ void scale_mask(const float* __restrict__ in, float* __restrict__ out) {
    int i = blockIdx.x * 256 + threadIdx.x;   // grid covers BB*SS
    out[i] = in[i] * 1.4426950408889634f;
}

// -------- transpose + cast all 4 weights: W (K x N f32) -> Wt (N x K bf16) --------
__global__ void transpose_cast4(const float* __restrict__ W0, const float* __restrict__ W1,
                                const float* __restrict__ W2, const float* __restrict__ W3,
                                unsigned short* __restrict__ out) {
    const float* in = blockIdx.z == 0 ? W0 : blockIdx.z == 1 ? W1 : blockIdx.z == 2 ? W2 : W3;
    unsigned short* o = out + (size_t)blockIdx.z * ((size_t)HHH * HHH);
    __shared__ float tile[32][33];
    int c0 = blockIdx.x * 32, r0 = blockIdx.y * 32;
    int tx = threadIdx.x, ty = threadIdx.y;   // (32, 8)
    #pragma unroll
    for (int i = 0; i < 32; i += 8)
        tile[ty + i][tx] = in[(size_t)(r0 + ty + i) * HHH + c0 + tx];
    __syncthreads();
    #pragma unroll
    for (int i = 0; i < 32; i += 8)
        o[(size_t)(c0 + ty + i) * HHH + r0 + tx] = f2bf(tile[tx][ty + i]);
}

// ---------------- 8-phase GEMM: C[M,N] = A[M,K] @ Bt[N,K]^T + bias ----------------
// BM=128, BN=256, BK=64. 8 waves (2M x 4N), per-wave 64x64 out, 512 threads.
// Triple-buffered LDS (3 x 48KB): 2-deep prefetch, counted vmcnt(6) at tile end.
template<int MODE>
__global__ __launch_bounds__(512, 2) void gemm8_bf16(
    const unsigned short* __restrict__ A,
    const unsigned short* __restrict__ Bt,
    const float* __restrict__ bias,
    void* __restrict__ Cout,
    int M, int N, int K)
{
    __shared__ __align__(16) unsigned char sm[147456];
    const int tid = threadIdx.x;
    const int wv = tid >> 6, ln = tid & 63;
    const int g = ln >> 4, r = ln & 15;
    const int wr = wv >> 2, wc = wv & 3;

    const int bid = blockIdx.x;
    const int lb = (bid & 7) * 32 + (bid >> 3);
    const int m0 = (lb & 31) * 128;
    const int n0 = (lb >> 5) * 256;

    unsigned srcA[2]; int ldsA[2];
    #pragma unroll
    for (int j = 0; j < 2; ++j) {
        int o = j * 8192 + tid * 16;
        int row = o >> 7;
        int lg = ((o >> 4) & 7) ^ (row & 7);
        srcA[j] = (unsigned)(m0 + row) * K + lg * 8;
        ldsA[j] = o;
    }
    unsigned srcB[4]; int ldsB[4];
    #pragma unroll
    for (int j = 0; j < 4; ++j) {
        int o = j * 8192 + tid * 16;
        int row = o >> 7;
        int lg = ((o >> 4) & 7) ^ (row & 7);
        srcB[j] = (unsigned)(n0 + row) * K + lg * 8;
        ldsB[j] = 16384 + o;
    }

    f32x4 acc[4][4];
    #pragma unroll
    for (int i = 0; i < 4; ++i)
        #pragma unroll
        for (int j = 0; j < 4; ++j)
            acc[i][j] = (f32x4){0.f, 0.f, 0.f, 0.f};

    const int NT = K >> 6;   // 32

    {
        unsigned char* b0 = sm;
        unsigned char* b1 = sm + 49152;
        #pragma unroll
        for (int j = 0; j < 2; ++j) gload16(A + srcA[j], b0 + ldsA[j]);
        #pragma unroll
        for (int j = 0; j < 4; ++j) gload16(Bt + srcB[j], b0 + ldsB[j]);
        #pragma unroll
        for (int j = 0; j < 2; ++j) gload16(A + srcA[j] + 64, b1 + ldsA[j]);
        #pragma unroll
        for (int j = 0; j < 4; ++j) gload16(Bt + srcB[j] + 64, b1 + ldsB[j]);
    }
    asm volatile("s_waitcnt vmcnt(6)" ::: "memory");
    __builtin_amdgcn_s_barrier();

    int csel = 0;
    int psel = 2;
    for (int t = 0; t < NT; ++t) {
        const unsigned char* Ab = sm + csel * 49152;
        const unsigned char* Bb = Ab + 16384;
        unsigned char* Pb = sm + psel * 49152;
        const bool pre = (t + 2 < NT);
        const int ko = (t + 2) * 64;

        bf16x8 af[2][2], bf[2][2];
        #define LDA(mi, ks) (*(const bf16x8*)(Ab + (wr * 64 + (mi) * 16 + r) * 128 + \
                             ((((ks) << 2) + g) ^ ((wr * 64 + (mi) * 16 + r) & 7)) * 16))
        #define LDB(ni, ks) (*(const bf16x8*)(Bb + (wc * 64 + (ni) * 16 + r) * 128 + \
                             ((((ks) << 2) + g) ^ ((wc * 64 + (ni) * 16 + r) & 7)) * 16))

        // ---- phase 0
        af[0][0] = LDA(0, 0); af[0][1] = LDA(0, 1);
        af[1][0] = LDA(1, 0); af[1][1] = LDA(1, 1);
        bf[0][0] = LDB(0, 0); bf[0][1] = LDB(0, 1);
        bf[1][0] = LDB(1, 0); bf[1][1] = LDB(1, 1);
        if (pre) { gload16(Bt + srcB[0] + ko, Pb + ldsB[0]);
                   gload16(Bt + srcB[1] + ko, Pb + ldsB[1]); }
        __builtin_amdgcn_s_barrier();
        asm volatile("s_waitcnt lgkmcnt(0)" ::: "memory");
        __builtin_amdgcn_s_setprio(1);
        #pragma unroll
        for (int mi = 0; mi < 2; ++mi)
            #pragma unroll
            for (int ni = 0; ni < 2; ++ni)
                #pragma unroll
                for (int ks = 0; ks < 2; ++ks)
                    acc[mi][ni] = MFMA16(af[mi][ks], bf[ni][ks], acc[mi][ni]);
        __builtin_amdgcn_s_setprio(0);
        __builtin_amdgcn_s_barrier();

        // ---- phase 1
        bf[0][0] = LDB(2, 0); bf[0][1] = LDB(2, 1);
        bf[1][0] = LDB(3, 0); bf[1][1] = LDB(3, 1);
        if (pre) { gload16(Bt + srcB[2] + ko, Pb + ldsB[2]);
                   gload16(Bt + srcB[3] + ko, Pb + ldsB[3]); }
        __builtin_amdgcn_s_barrier();
        asm volatile("s_waitcnt lgkmcnt(0)" ::: "memory");
        __builtin_amdgcn_s_setprio(1);
        #pragma unroll
        for (int mi = 0; mi < 2; ++mi)
            #pragma unroll
            for (int ni = 0; ni < 2; ++ni)
                #pragma unroll
                for (int ks = 0; ks < 2; ++ks)
                    acc[mi][ni + 2] = MFMA16(af[mi][ks], bf[ni][ks], acc[mi][ni + 2]);
        __builtin_amdgcn_s_setprio(0);
        __builtin_amdgcn_s_barrier();

        // ---- phase 2
        af[0][0] = LDA(2, 0); af[0][1] = LDA(2, 1);
        af[1][0] = LDA(3, 0); af[1][1] = LDA(3, 1);
        if (pre) { gload16(A + srcA[0] + ko, Pb + ldsA[0]);
                   gload16(A + srcA[1] + ko, Pb + ldsA[1]); }
        __builtin_amdgcn_s_barrier();
        asm volatile("s_waitcnt lgkmcnt(0)" ::: "memory");
        __builtin_amdgcn_s_setprio(1);
        #pragma unroll
        for (int mi = 0; mi < 2; ++mi)
            #pragma unroll
            for (int ni = 0; ni < 2; ++ni)
                #pragma unroll
                for (int ks = 0; ks < 2; ++ks)
                    acc[mi + 2][ni + 2] = MFMA16(af[mi][ks], bf[ni][ks], acc[mi + 2][ni + 2]);
        __builtin_amdgcn_s_setprio(0);
        __builtin_amdgcn_s_barrier();

        // ---- phase 3
        bf[0][0] = LDB(0, 0); bf[0][1] = LDB(0, 1);
        bf[1][0] = LDB(1, 0); bf[1][1] = LDB(1, 1);
        __builtin_amdgcn_s_barrier();
        asm volatile("s_waitcnt lgkmcnt(0)" ::: "memory");
        __builtin_amdgcn_s_setprio(1);
        #pragma unroll
        for (int mi = 0; mi < 2; ++mi)
            #pragma unroll
            for (int ni = 0; ni < 2; ++ni)
                #pragma unroll
                for (int ks = 0; ks < 2; ++ks)
                    acc[mi + 2][ni] = MFMA16(af[mi][ks], bf[ni][ks], acc[mi + 2][ni]);
        __builtin_amdgcn_s_setprio(0);
        __builtin_amdgcn_s_barrier();

        if (pre) asm volatile("s_waitcnt vmcnt(6)" ::: "memory");
        else     asm volatile("s_waitcnt vmcnt(0)" ::: "memory");
        __builtin_amdgcn_s_barrier();

        csel = (csel == 2) ? 0 : csel + 1;
        psel = (psel == 2) ? 0 : psel + 1;
        #undef LDA
        #undef LDB
    }

    #pragma unroll
    for (int mt = 0; mt < 4; ++mt) {
        #pragma unroll
        for (int nt = 0; nt < 4; ++nt) {
            int col = n0 + wc * 64 + nt * 16 + r;
            float bvv = bias[col];
            f32x4 a = acc[mt][nt];
            int mrow = m0 + wr * 64 + mt * 16 + g * 4;
            if (MODE == 0) {
                #pragma unroll
                for (int q = 0; q < 4; ++q)
                    ((unsigned short*)Cout)[(size_t)(mrow + q) * N + col] = f2bf(a[q] + bvv);
            } else if (MODE == 2) {
                #pragma unroll
                for (int q = 0; q < 4; ++q)
                    ((float*)Cout)[(size_t)(mrow + q) * N + col] = a[q] + bvv;
            } else {
                int b = mrow >> 11, s0x = mrow & 2047;
                ushort4 o;
                o.x = f2bf(a[0] + bvv); o.y = f2bf(a[1] + bvv);
                o.z = f2bf(a[2] + bvv); o.w = f2bf(a[3] + bvv);
                *(ushort4*)((unsigned short*)Cout + ((size_t)(b * 2048 + col)) * 2048 + s0x) = o;
            }
        }
    }
}

// ---------------- flash attention: no KV-split, KVBLK=32, 3-deep pipeline ----------------
// 512 blocks (2/CU), 4 waves x 32 q-rows. Triple-buffered {K[32][128], Vt[128][32]}
// (3 x 16KB = 48KB). Counted vmcnt(4) + raw barrier per tile — no vmcnt(0) drains.
__global__ __launch_bounds__(256, 2) void attn_fwd(
    const unsigned short* __restrict__ Q,
    const unsigned short* __restrict__ K,
    const unsigned short* __restrict__ V,
    const float* __restrict__ maskl2,   // mask * log2(e)
    unsigned short* __restrict__ O)
{
    __shared__ __align__(16) unsigned char sm[49152];
    const int tid = threadIdx.x, wv = tid >> 6, ln = tid & 63;
    const int hi = ln >> 5, qr = ln & 31;

    // XCD-bijective swizzle (512 blocks = 8 XCD x 64): XCD owns 4 full heads
    const int bid = blockIdx.x;
    const int lb = (bid & 7) * 64 + (bid >> 3);
    const int qb = lb & 15;
    const int bh = lb >> 4;
    const int h = bh & 15, b = bh >> 4;

    const size_t rowQ0 = (size_t)(b * 2048 + qb * 128 + wv * 32);
    const float SCL2 = 0.08838834764831845f * 1.4426950408889634f; // scale*log2e

    // staging precompute: K tile [32][128] (256B rows, 16 granules, ^(row&7));
    //                     Vt tile [128][32] (64B rows, 4 granules, ^((d>>1)&3))
    unsigned srcK[2], srcV[2];
    int ldsK[2], ldsV[2];
    #pragma unroll
    for (int i = 0; i < 2; ++i) {
        int ch = wv * 2 + i;
        int o = ch * 1024 + ln * 16;
        { int row = o >> 8; int gl = ((o >> 4) & 15) ^ (row & 7);
          srcK[i] = (unsigned)((b * 2048 + row) * 2048 + h * 128 + gl * 8);
          ldsK[i] = o; }
        { int d = o >> 6; int gl = ((o >> 4) & 3) ^ ((d >> 1) & 3);
          srcV[i] = (unsigned)((b * 2048 + h * 128 + d) * 2048 + gl * 8);
          ldsV[i] = 8192 + o; }
    }

    #define STAGE(t, base) { \
        _Pragma("unroll") \
        for (int i = 0; i < 2; ++i) { \
            gload16(K + srcK[i] + (unsigned)(t) * (32u * 2048u), sm + (base) + ldsK[i]); \
            gload16(V + srcV[i] + (unsigned)(t) * 32u, sm + (base) + ldsV[i]); \
        } }

    // prologue: stage tiles 0,1,2 into bufs 0,1,2 (12 loads/wave)
    STAGE(0, 0); STAGE(1, 16384); STAGE(2, 32768);

    // Q fragments (B-operand): col = qr, k = hi*8+j, 8 k-steps of 16
    bf16x8 qf[8];
    #pragma unroll
    for (int ks = 0; ks < 8; ++ks)
        qf[ks] = *(const bf16x8*)(Q + (rowQ0 + qr) * 2048 + h * 128 + ks * 16 + hi * 8);

    f32x16 acc[4];
    #pragma unroll
    for (int i = 0; i < 4; ++i)
        #pragma unroll
        for (int j = 0; j < 16; ++j)
            acc[i][j] = 0.f;
    float mr = -3.0e38f, lr = 0.f;   // per-lane: q-row = qr

    const float* mb = maskl2 + b * 2048;

    // tile 0 ready: of 12 outstanding, wait until only 8 (tiles 1,2) remain
    asm volatile("s_waitcnt vmcnt(8)" ::: "memory");
    __builtin_amdgcn_s_barrier();

    int bufo = 0;
    for (int t = 0; t < 64; ++t) {
        const unsigned char* Kt = sm + bufo;
        const unsigned char* Vt = Kt + 8192;

        // mask values (pre-scaled): key = t*32 + rg*8 + hi*4 + q4
        f32x4 mk[4];
        #pragma unroll
        for (int rg = 0; rg < 4; ++rg)
            mk[rg] = *(const f32x4*)(mb + t * 32 + rg * 8 + hi * 4);

        // S^T = K Q^T (keys 0..31 on rows, q on cols)
        f32x16 sf;
        #pragma unroll
        for (int j = 0; j < 16; ++j) sf[j] = 0.f;
        __builtin_amdgcn_s_setprio(1);
        #pragma unroll
        for (int ks = 0; ks < 8; ++ks) {
            int s0 = (2 * ks + hi) ^ (qr & 7);
            bf16x8 kf = *(const bf16x8*)(Kt + qr * 256 + s0 * 16);
            sf = MFMA32(kf, qf[ks], sf);
        }
        __builtin_amdgcn_s_setprio(0);

        // scale + mask (log2 domain; mask pre-scaled)
        float sv[16];
        #pragma unroll
        for (int reg = 0; reg < 16; ++reg)
            sv[reg] = sf[reg] * SCL2 + mk[reg >> 2][reg & 3];

        // row max: balanced tree over 16 in-lane, then cross-half permlane
        float mx[8];
        #pragma unroll
        for (int j = 0; j < 8; ++j)
            mx[j] = fmaxf(sv[2 * j], sv[2 * j + 1]);
        float m01 = fmaxf(fmaxf(fmaxf(mx[0], mx[1]), fmaxf(mx[2], mx[3])),
                          fmaxf(fmaxf(mx[4], mx[5]), fmaxf(mx[6], mx[7])));
        float2 mp = xswap(m01);
        float mt = fmaxf(mp.x, mp.y);

        // defer-max
        float alpha = 1.f;
        int allskip = __all(mt <= mr + 8.f);
        if (!allskip) {
            float nm = fmaxf(mr, mt);
            alpha = __builtin_amdgcn_exp2f(mr - nm);
            mr = nm;
            #pragma unroll
            for (int dblk = 0; dblk < 4; ++dblk)
                #pragma unroll
                for (int reg = 0; reg < 16; ++reg)
                    acc[dblk][reg] *= alpha;
        }

        // P = exp2(S - m), row sum (4 partials), cross-half permlane
        float s0 = 0.f, s1 = 0.f, s2 = 0.f, s3 = 0.f;
        #pragma unroll
        for (int reg = 0; reg < 16; reg += 4) {
            float p0 = __builtin_amdgcn_exp2f(sv[reg + 0] - mr);
            float p1 = __builtin_amdgcn_exp2f(sv[reg + 1] - mr);
            float p2 = __builtin_amdgcn_exp2f(sv[reg + 2] - mr);
            float p3 = __builtin_amdgcn_exp2f(sv[reg + 3] - mr);
            sv[reg + 0] = p0; sv[reg + 1] = p1;
            sv[reg + 2] = p2; sv[reg + 3] = p3;
            s0 += p0; s1 += p1; s2 += p2; s3 += p3;
        }
        float rsl = (s0 + s1) + (s2 + s3);
        float2 rp = xswap(rsl);
        float rs = rp.x + rp.y;
        lr = lr * alpha + rs;

        // P -> PV B-fragments via permlane32_swap (kb16 in {0,1})
        bf16x8 pfr[2];
        #pragma unroll
        for (int kb16 = 0; kb16 < 2; ++kb16) {
            unsigned W00 = packbf(sv[(2*kb16+0)*4 + 0], sv[(2*kb16+0)*4 + 1]);
            unsigned W01 = packbf(sv[(2*kb16+0)*4 + 2], sv[(2*kb16+0)*4 + 3]);
            unsigned W10 = packbf(sv[(2*kb16+1)*4 + 0], sv[(2*kb16+1)*4 + 1]);
            unsigned W11 = packbf(sv[(2*kb16+1)*4 + 2], sv[(2*kb16+1)*4 + 3]);
            pswap(W00, W10);
            pswap(W01, W11);
            union { unsigned w[4]; bf16x8 v; } u;
            u.w[0] = W00; u.w[1] = W01; u.w[2] = W10; u.w[3] = W11;
            pfr[kb16] = u.v;
        }

        // O^T += V^T P^T
        __builtin_amdgcn_s_setprio(1);
        #pragma unroll
        for (int dblk = 0; dblk < 4; ++dblk) {
            int d = dblk * 32 + qr;
            f32x16 a = acc[dblk];
            #pragma unroll
            for (int kb16 = 0; kb16 < 2; ++kb16) {
                int s = (2 * kb16 + hi) ^ ((d >> 1) & 3);
                bf16x8 vf = *(const bf16x8*)(Vt + d * 64 + s * 16);
                a = MFMA32(vf, pfr[kb16], a);
            }
            acc[dblk] = a;
        }
        __builtin_amdgcn_s_setprio(0);

        // tile end: t+1's loads done (only t+2's 4 may remain); all waves done with buf t
        asm volatile("s_waitcnt vmcnt(4)" ::: "memory");
        __builtin_amdgcn_s_barrier();

        // refill just-freed buffer with tile t+3
        if (t + 3 < 64) STAGE(t + 3, bufo);
        bufo = (bufo == 32768) ? 0 : bufo + 16384;
    }

    // epilogue: O[qrow][d], d = dblk*32 + rg*8 + 4*hi + q4; per-lane 1/l
    float linv = 1.f / lr;
    unsigned short* orow = O + (rowQ0 + qr) * 2048 + h * 128;
    #pragma unroll
    for (int dblk = 0; dblk < 4; ++dblk)
        #pragma unroll
        for (int rg = 0; rg < 4; ++rg) {
            float v0 = acc[dblk][rg * 4 + 0] * linv;
            float v1 = acc[dblk][rg * 4 + 1] * linv;
            float v2 = acc[dblk][rg * 4 + 2] * linv;
            float v3 = acc[dblk][rg * 4 + 3] * linv;
            uint2 o;
            o.x = packbf(v0, v1);
            o.y = packbf(v2, v3);
            *(uint2*)(orow + dblk * 32 + rg * 8 + hi * 4) = o;
        }
    #undef STAGE
}

// ---------------- host launch ----------------
extern "C" void kernel_launch(void* const* d_in, const int* in_sizes, int n_in,
                              void* d_out, int out_size, void* d_ws, size_t ws_size,
                              hipStream_t stream)
{
    (void)in_sizes; (void)n_in; (void)out_size; (void)ws_size;
    const float* x    = (const float*)d_in[0];
    const float* mask = (const float*)d_in[1];
    const float* Wq   = (const float*)d_in[2];
    const float* bq   = (const float*)d_in[3];
    const float* Wk   = (const float*)d_in[4];
    const float* bk   = (const float*)d_in[5];
    const float* Wv   = (const float*)d_in[6];
    const float* bv   = (const float*)d_in[7];
    const float* Wo   = (const float*)d_in[8];
    const float* bo   = (const float*)d_in[9];
    float* out = (float*)d_out;

    char* ws = (char*)d_ws;
    //  0..16  xb (bf16 x)
    // 16..40  Wqt,Wkt,Wvt (contiguous; Ab reuses 16.., maskl2 reuses 32.. once dead)
    // 40..48  Wot (live to the end)
    // 48..64  Qb   64..80 Kb   80..96 Vtb
    unsigned short* xb  = (unsigned short*)(ws);
    unsigned short* Wqt = (unsigned short*)(ws + (16u << 20));
    unsigned short* Wkt = (unsigned short*)(ws + (24u << 20));
    unsigned short* Wvt = (unsigned short*)(ws + (32u << 20));
    unsigned short* Wot = (unsigned short*)(ws + (40u << 20));
    unsigned short* Qb  = (unsigned short*)(ws + (48u << 20));
    unsigned short* Kb  = (unsigned short*)(ws + (64u << 20));
    unsigned short* Vtb = (unsigned short*)(ws + (80u << 20));
    unsigned short* Ab  = (unsigned short*)(ws + (16u << 20));   // dead Wqt/Wkt
    float*          mkl = (float*)(ws + (32u << 20));            // dead Wvt

    cast_f32_bf16<<<2048, 256, 0, stream>>>(x, xb, MTOT * HHH);
    transpose_cast4<<<dim3(64, 64, 4), dim3(32, 8), 0, stream>>>(Wq, Wk, Wv, Wo, Wqt);

    gemm8_bf16<0><<<256, 512, 0, stream>>>(xb, Wqt, bq, Qb,  MTOT, HHH, HHH);
    gemm8_bf16<0><<<256, 512, 0, stream>>>(xb, Wkt, bk, Kb,  MTOT, HHH, HHH);
    gemm8_bf16<1><<<256, 512, 0, stream>>>(xb, Wvt, bv, Vtb, MTOT, HHH, HHH);

    scale_mask<<<(BB * SS) / 256, 256, 0, stream>>>(mask, mkl);   // after V GEMM (Wvt dead)
    attn_fwd<<<512, 256, 0, stream>>>(Qb, Kb, Vtb, mkl, Ab);

    gemm8_bf16<2><<<256, 512, 0, stream>>>(Ab, Wot, bo, out, MTOT, HHH, HHH);
}

// Round 9
// 279.599 us; speedup vs baseline: 1.4441x; 1.0428x over previous
//
#include <hip/hip_runtime.h>
#include <hip/hip_bf16.h>
#include <stdint.h>

// Problem constants
#define BB   2
#define SS   2048
#define HHH  2048
#define NHH  16
#define HDD  128
#define MTOT 4096   // BB*SS

typedef __bf16 bf16x8 __attribute__((ext_vector_type(8)));
typedef float  f32x4  __attribute__((ext_vector_type(4)));
typedef float  f32x16 __attribute__((ext_vector_type(16)));

#define MFMA16(a, b, c) __builtin_amdgcn_mfma_f32_16x16x32_bf16((a), (b), (c), 0, 0, 0)
#define MFMA32(a, b, c) __builtin_amdgcn_mfma_f32_32x32x16_bf16((a), (b), (c), 0, 0, 0)

__device__ __forceinline__ unsigned short f2bf(float f) {
    union { float f; unsigned u; } v; v.f = f;
    unsigned r = v.u + 0x7FFFu + ((v.u >> 16) & 1u);   // RNE
    return (unsigned short)(r >> 16);
}

__device__ __forceinline__ unsigned packbf(float a, float b) {
    union { __bf16 h[2]; unsigned u; } p;
    p.h[0] = (__bf16)a; p.h[1] = (__bf16)b;
    return p.u;
}

// v_permlane32_swap_b32: a' = [a.lo32, b.lo32], b' = [a.hi32, b.hi32]
__device__ __forceinline__ void pswap(unsigned &a, unsigned &b) {
    asm("v_permlane32_swap_b32 %0, %1" : "+v"(a), "+v"(b));
}

// cross-half (lane ^ 32) pair: returns {own-half view, other-half view}
__device__ __forceinline__ float2 xswap(float x) {
    unsigned a = __builtin_bit_cast(unsigned, x);
    unsigned b;
    asm("v_mov_b32 %0, %1" : "=v"(b) : "v"(a));   // force distinct register
    asm("v_permlane32_swap_b32 %0, %1" : "+v"(a), "+v"(b));
    return make_float2(__builtin_bit_cast(float, a), __builtin_bit_cast(float, b));
}

// async global->LDS, 16B per lane. LDS dest is wave-uniform base + lane*16.
__device__ __forceinline__ void gload16(const void* src, void* lds) {
    __builtin_amdgcn_global_load_lds(
        (__attribute__((address_space(1))) void*)src,
        (__attribute__((address_space(3))) void*)lds,
        16, 0, 0);
}

// ---------------- cast f32 -> bf16 (vectorized) ----------------
__global__ void cast_f32_bf16(const float* __restrict__ in,
                              unsigned short* __restrict__ out, int n) {
    int i = (blockIdx.x * blockDim.x + threadIdx.x) * 4;
    int stride = gridDim.x * blockDim.x * 4;
    for (; i < n; i += stride) {
        float4 v = *(const float4*)(in + i);
        ushort4 o;
        o.x = f2bf(v.x); o.y = f2bf(v.y); o.z = f2bf(v.z); o.w = f2bf(v.w);
        *(ushort4*)(out + i) = o;
    }
}

// ---------------- pre-scale mask by log2(e) ----------------
__global__ void scale_mask(const float* __restrict__ in, float* __restrict__ out) {
    int i = blockIdx.x * 256 + threadIdx.x;   // grid covers BB*SS
    out[i] = in[i] * 1.4426950408889634f;
}

// -------- transpose + cast all 4 weights: W (K x N f32) -> Wt (N x K bf16) --------
__global__ void transpose_cast4(const float* __restrict__ W0, const float* __restrict__ W1,
                                const float* __restrict__ W2, const float* __restrict__ W3,
                                unsigned short* __restrict__ out) {
    const float* in = blockIdx.z == 0 ? W0 : blockIdx.z == 1 ? W1 : blockIdx.z == 2 ? W2 : W3;
    unsigned short* o = out + (size_t)blockIdx.z * ((size_t)HHH * HHH);
    __shared__ float tile[32][33];
    int c0 = blockIdx.x * 32, r0 = blockIdx.y * 32;
    int tx = threadIdx.x, ty = threadIdx.y;   // (32, 8)
    #pragma unroll
    for (int i = 0; i < 32; i += 8)
        tile[ty + i][tx] = in[(size_t)(r0 + ty + i) * HHH + c0 + tx];
    __syncthreads();
    #pragma unroll
    for (int i = 0; i < 32; i += 8)
        o[(size_t)(c0 + ty + i) * HHH + r0 + tx] = f2bf(tile[tx][ty + i]);
}

// ---------------- 2-phase GEMM: C[M,N] = A[M,K] @ Bt[N,K]^T + bias ----------------
// BM=128, BN=256, BK=64. 8 waves (2M x 4N), per-wave 64x64 out, 512 threads.
// Triple-buffered LDS (3 x 48KB): 2-deep prefetch, counted vmcnt(6) at tile end.
// 2 phases/K-tile, 16 MFMA each; B fragments held in registers across phases.
template<int MODE>
__global__ __launch_bounds__(512, 2) void gemm8_bf16(
    const unsigned short* __restrict__ A,
    const unsigned short* __restrict__ Bt,
    const float* __restrict__ bias,
    void* __restrict__ Cout,
    int M, int N, int K)
{
    __shared__ __align__(16) unsigned char sm[147456];
    const int tid = threadIdx.x;
    const int wv = tid >> 6, ln = tid & 63;
    const int g = ln >> 4, r = ln & 15;
    const int wr = wv >> 2, wc = wv & 3;

    const int bid = blockIdx.x;
    const int lb = (bid & 7) * 32 + (bid >> 3);
    const int m0 = (lb & 31) * 128;
    const int n0 = (lb >> 5) * 256;

    unsigned srcA[2]; int ldsA[2];
    #pragma unroll
    for (int j = 0; j < 2; ++j) {
        int o = j * 8192 + tid * 16;
        int row = o >> 7;
        int lg = ((o >> 4) & 7) ^ (row & 7);
        srcA[j] = (unsigned)(m0 + row) * K + lg * 8;
        ldsA[j] = o;
    }
    unsigned srcB[4]; int ldsB[4];
    #pragma unroll
    for (int j = 0; j < 4; ++j) {
        int o = j * 8192 + tid * 16;
        int row = o >> 7;
        int lg = ((o >> 4) & 7) ^ (row & 7);
        srcB[j] = (unsigned)(n0 + row) * K + lg * 8;
        ldsB[j] = 16384 + o;
    }

    f32x4 acc[4][4];
    #pragma unroll
    for (int i = 0; i < 4; ++i)
        #pragma unroll
        for (int j = 0; j < 4; ++j)
            acc[i][j] = (f32x4){0.f, 0.f, 0.f, 0.f};

    const int NT = K >> 6;   // 32

    {
        unsigned char* b0 = sm;
        unsigned char* b1 = sm + 49152;
        #pragma unroll
        for (int j = 0; j < 2; ++j) gload16(A + srcA[j], b0 + ldsA[j]);
        #pragma unroll
        for (int j = 0; j < 4; ++j) gload16(Bt + srcB[j], b0 + ldsB[j]);
        #pragma unroll
        for (int j = 0; j < 2; ++j) gload16(A + srcA[j] + 64, b1 + ldsA[j]);
        #pragma unroll
        for (int j = 0; j < 4; ++j) gload16(Bt + srcB[j] + 64, b1 + ldsB[j]);
    }
    asm volatile("s_waitcnt vmcnt(6)" ::: "memory");
    __builtin_amdgcn_s_barrier();

    int csel = 0;
    int psel = 2;
    for (int t = 0; t < NT; ++t) {
        const unsigned char* Ab = sm + csel * 49152;
        const unsigned char* Bb = Ab + 16384;
        unsigned char* Pb = sm + psel * 49152;
        const bool pre = (t + 2 < NT);
        const int ko = (t + 2) * 64;

        bf16x8 af[2][2], bfr[4][2];
        #define LDA(mi, ks) (*(const bf16x8*)(Ab + (wr * 64 + (mi) * 16 + r) * 128 + \
                             ((((ks) << 2) + g) ^ ((wr * 64 + (mi) * 16 + r) & 7)) * 16))
        #define LDB(ni, ks) (*(const bf16x8*)(Bb + (wc * 64 + (ni) * 16 + r) * 128 + \
                             ((((ks) << 2) + g) ^ ((wc * 64 + (ni) * 16 + r) & 7)) * 16))

        // ---- phase A: A rows {0,1} x B cols {0..3}; stage B0,B1,B2
        af[0][0] = LDA(0, 0); af[0][1] = LDA(0, 1);
        af[1][0] = LDA(1, 0); af[1][1] = LDA(1, 1);
        #pragma unroll
        for (int ni = 0; ni < 4; ++ni) {
            bfr[ni][0] = LDB(ni, 0);
            bfr[ni][1] = LDB(ni, 1);
        }
        if (pre) { gload16(Bt + srcB[0] + ko, Pb + ldsB[0]);
                   gload16(Bt + srcB[1] + ko, Pb + ldsB[1]);
                   gload16(Bt + srcB[2] + ko, Pb + ldsB[2]); }
        __builtin_amdgcn_s_barrier();
        asm volatile("s_waitcnt lgkmcnt(0)" ::: "memory");
        __builtin_amdgcn_s_setprio(1);
        #pragma unroll
        for (int mi = 0; mi < 2; ++mi)
            #pragma unroll
            for (int ni = 0; ni < 4; ++ni)
                #pragma unroll
                for (int ks = 0; ks < 2; ++ks)
                    acc[mi][ni] = MFMA16(af[mi][ks], bfr[ni][ks], acc[mi][ni]);
        __builtin_amdgcn_s_setprio(0);
        __builtin_amdgcn_s_barrier();

        // ---- phase B: A rows {2,3} x B cols {0..3} (B held); stage B3,A0,A1
        af[0][0] = LDA(2, 0); af[0][1] = LDA(2, 1);
        af[1][0] = LDA(3, 0); af[1][1] = LDA(3, 1);
        if (pre) { gload16(Bt + srcB[3] + ko, Pb + ldsB[3]);
                   gload16(A + srcA[0] + ko, Pb + ldsA[0]);
                   gload16(A + srcA[1] + ko, Pb + ldsA[1]); }
        __builtin_amdgcn_s_barrier();
        asm volatile("s_waitcnt lgkmcnt(0)" ::: "memory");
        __builtin_amdgcn_s_setprio(1);
        #pragma unroll
        for (int mi = 0; mi < 2; ++mi)
            #pragma unroll
            for (int ni = 0; ni < 4; ++ni)
                #pragma unroll
                for (int ks = 0; ks < 2; ++ks)
                    acc[mi + 2][ni] = MFMA16(af[mi][ks], bfr[ni][ks], acc[mi + 2][ni]);
        __builtin_amdgcn_s_setprio(0);

        // tile end: tile t+1's 6 loads are the oldest outstanding
        if (pre) asm volatile("s_waitcnt vmcnt(6)" ::: "memory");
        else     asm volatile("s_waitcnt vmcnt(0)" ::: "memory");
        __builtin_amdgcn_s_barrier();

        csel = (csel == 2) ? 0 : csel + 1;
        psel = (psel == 2) ? 0 : psel + 1;
        #undef LDA
        #undef LDB
    }

    #pragma unroll
    for (int mt = 0; mt < 4; ++mt) {
        #pragma unroll
        for (int nt = 0; nt < 4; ++nt) {
            int col = n0 + wc * 64 + nt * 16 + r;
            float bvv = bias[col];
            f32x4 a = acc[mt][nt];
            int mrow = m0 + wr * 64 + mt * 16 + g * 4;
            if (MODE == 0) {
                #pragma unroll
                for (int q = 0; q < 4; ++q)
                    ((unsigned short*)Cout)[(size_t)(mrow + q) * N + col] = f2bf(a[q] + bvv);
            } else if (MODE == 2) {
                #pragma unroll
                for (int q = 0; q < 4; ++q)
                    ((float*)Cout)[(size_t)(mrow + q) * N + col] = a[q] + bvv;
            } else {
                int b = mrow >> 11, s0x = mrow & 2047;
                ushort4 o;
                o.x = f2bf(a[0] + bvv); o.y = f2bf(a[1] + bvv);
                o.z = f2bf(a[2] + bvv); o.w = f2bf(a[3] + bvv);
                *(ushort4*)((unsigned short*)Cout + ((size_t)(b * 2048 + col)) * 2048 + s0x) = o;
            }
        }
    }
}

// ---------------- flash attention: KVBLK=32, 3-deep pipeline, mask in LDS ----------------
// 512 blocks (2/CU), 4 waves x 32 q-rows. Triple-buffered {K[32][128], Vt[128][32]}
// (3 x 16KB) + full mask row in LDS (8KB). Zero VMEM in the loop except 4 STAGE loads
// -> counted vmcnt(4) + raw barrier per tile works as designed (no compiler drains).
__global__ __launch_bounds__(256, 2) void attn_fwd(
    const unsigned short* __restrict__ Q,
    const unsigned short* __restrict__ K,
    const unsigned short* __restrict__ V,
    const float* __restrict__ maskl2,   // mask * log2(e)
    unsigned short* __restrict__ O)
{
    __shared__ __align__(16) unsigned char sm[57344]; // 3 x 16KB KV bufs + 8KB mask @49152
    const int tid = threadIdx.x, wv = tid >> 6, ln = tid & 63;
    const int hi = ln >> 5, qr = ln & 31;

    // XCD-bijective swizzle (512 blocks = 8 XCD x 64): XCD owns 4 full heads
    const int bid = blockIdx.x;
    const int lb = (bid & 7) * 64 + (bid >> 3);
    const int qb = lb & 15;
    const int bh = lb >> 4;
    const int h = bh & 15, b = bh >> 4;

    const size_t rowQ0 = (size_t)(b * 2048 + qb * 128 + wv * 32);
    const float SCL2 = 0.08838834764831845f * 1.4426950408889634f; // scale*log2e

    // staging precompute: K tile [32][128] (256B rows, 16 granules, ^(row&7));
    //                     Vt tile [128][32] (64B rows, 4 granules, ^((d>>1)&3))
    unsigned srcK[2], srcV[2];
    int ldsK[2], ldsV[2];
    #pragma unroll
    for (int i = 0; i < 2; ++i) {
        int ch = wv * 2 + i;
        int o = ch * 1024 + ln * 16;
        { int row = o >> 8; int gl = ((o >> 4) & 15) ^ (row & 7);
          srcK[i] = (unsigned)((b * 2048 + row) * 2048 + h * 128 + gl * 8);
          ldsK[i] = o; }
        { int d = o >> 6; int gl = ((o >> 4) & 3) ^ ((d >> 1) & 3);
          srcV[i] = (unsigned)((b * 2048 + h * 128 + d) * 2048 + gl * 8);
          ldsV[i] = 8192 + o; }
    }

    #define STAGE(t, base) { \
        _Pragma("unroll") \
        for (int i = 0; i < 2; ++i) { \
            gload16(K + srcK[i] + (unsigned)(t) * (32u * 2048u), sm + (base) + ldsK[i]); \
            gload16(V + srcV[i] + (unsigned)(t) * 32u, sm + (base) + ldsV[i]); \
        } }

    // prologue: mask row -> LDS (2 gloads/wave, oldest), then tiles 0,1,2
    #pragma unroll
    for (int i = 0; i < 2; ++i)
        gload16(maskl2 + b * 2048 + wv * 512 + i * 256 + ln * 4,
                sm + 49152 + wv * 2048 + i * 1024);
    STAGE(0, 0); STAGE(1, 16384); STAGE(2, 32768);

    // Q fragments (B-operand): col = qr, k = hi*8+j, 8 k-steps of 16
    bf16x8 qf[8];
    #pragma unroll
    for (int ks = 0; ks < 8; ++ks)
        qf[ks] = *(const bf16x8*)(Q + (rowQ0 + qr) * 2048 + h * 128 + ks * 16 + hi * 8);

    f32x16 acc[4];
    #pragma unroll
    for (int i = 0; i < 4; ++i)
        #pragma unroll
        for (int j = 0; j < 16; ++j)
            acc[i][j] = 0.f;
    float mr = -3.0e38f, lr = 0.f;   // per-lane: q-row = qr

    const float* ml = (const float*)(sm + 49152);

    // of 14 outstanding (2 mask + 12 KV), wait until only 8 (tiles 1,2) remain
    asm volatile("s_waitcnt vmcnt(8)" ::: "memory");
    __builtin_amdgcn_s_barrier();

    int bufo = 0;
    for (int t = 0; t < 64; ++t) {
        const unsigned char* Kt = sm + bufo;
        const unsigned char* Vt = Kt + 8192;

        // mask values from LDS (broadcast within 16-lane groups)
        f32x4 mk[4];
        #pragma unroll
        for (int rg = 0; rg < 4; ++rg)
            mk[rg] = *(const f32x4*)(ml + t * 32 + rg * 8 + hi * 4);

        // S^T = K Q^T : two independent 4-deep MFMA chains
        f32x16 sfA, sfB;
        #pragma unroll
        for (int j = 0; j < 16; ++j) { sfA[j] = 0.f; sfB[j] = 0.f; }
        __builtin_amdgcn_s_setprio(1);
        #pragma unroll
        for (int ks = 0; ks < 4; ++ks) {
            int s0 = (2 * ks + hi) ^ (qr & 7);
            bf16x8 kf = *(const bf16x8*)(Kt + qr * 256 + s0 * 16);
            sfA = MFMA32(kf, qf[ks], sfA);
        }
        #pragma unroll
        for (int ks = 4; ks < 8; ++ks) {
            int s0 = (2 * ks + hi) ^ (qr & 7);
            bf16x8 kf = *(const bf16x8*)(Kt + qr * 256 + s0 * 16);
            sfB = MFMA32(kf, qf[ks], sfB);
        }
        __builtin_amdgcn_s_setprio(0);

        // combine + scale + mask (log2 domain; mask pre-scaled)
        float sv[16];
        #pragma unroll
        for (int reg = 0; reg < 16; ++reg)
            sv[reg] = (sfA[reg] + sfB[reg]) * SCL2 + mk[reg >> 2][reg & 3];

        // row max: balanced tree over 16 in-lane, then cross-half permlane
        float mx[8];
        #pragma unroll
        for (int j = 0; j < 8; ++j)
            mx[j] = fmaxf(sv[2 * j], sv[2 * j + 1]);
        float m01 = fmaxf(fmaxf(fmaxf(mx[0], mx[1]), fmaxf(mx[2], mx[3])),
                          fmaxf(fmaxf(mx[4], mx[5]), fmaxf(mx[6], mx[7])));
        float2 mp = xswap(m01);
        float mt = fmaxf(mp.x, mp.y);

        // defer-max
        float alpha = 1.f;
        int allskip = __all(mt <= mr + 8.f);
        if (!allskip) {
            float nm = fmaxf(mr, mt);
            alpha = __builtin_amdgcn_exp2f(mr - nm);
            mr = nm;
            #pragma unroll
            for (int dblk = 0; dblk < 4; ++dblk)
                #pragma unroll
                for (int reg = 0; reg < 16; ++reg)
                    acc[dblk][reg] *= alpha;
        }

        // P = exp2(S - m), row sum (4 partials), cross-half permlane
        float s0 = 0.f, s1 = 0.f, s2 = 0.f, s3 = 0.f;
        #pragma unroll
        for (int reg = 0; reg < 16; reg += 4) {
            float p0 = __builtin_amdgcn_exp2f(sv[reg + 0] - mr);
            float p1 = __builtin_amdgcn_exp2f(sv[reg + 1] - mr);
            float p2 = __builtin_amdgcn_exp2f(sv[reg + 2] - mr);
            float p3 = __builtin_amdgcn_exp2f(sv[reg + 3] - mr);
            sv[reg + 0] = p0; sv[reg + 1] = p1;
            sv[reg + 2] = p2; sv[reg + 3] = p3;
            s0 += p0; s1 += p1; s2 += p2; s3 += p3;
        }
        float rsl = (s0 + s1) + (s2 + s3);
        float2 rp = xswap(rsl);
        float rs = rp.x + rp.y;
        lr = lr * alpha + rs;

        // P -> PV B-fragments via permlane32_swap (kb16 in {0,1})
        bf16x8 pfr[2];
        #pragma unroll
        for (int kb16 = 0; kb16 < 2; ++kb16) {
            unsigned W00 = packbf(sv[(2*kb16+0)*4 + 0], sv[(2*kb16+0)*4 + 1]);
            unsigned W01 = packbf(sv[(2*kb16+0)*4 + 2], sv[(2*kb16+0)*4 + 3]);
            unsigned W10 = packbf(sv[(2*kb16+1)*4 + 0], sv[(2*kb16+1)*4 + 1]);
            unsigned W11 = packbf(sv[(2*kb16+1)*4 + 2], sv[(2*kb16+1)*4 + 3]);
            pswap(W00, W10);
            pswap(W01, W11);
            union { unsigned w[4]; bf16x8 v; } u;
            u.w[0] = W00; u.w[1] = W01; u.w[2] = W10; u.w[3] = W11;
            pfr[kb16] = u.v;
        }

        // O^T += V^T P^T
        __builtin_amdgcn_s_setprio(1);
        #pragma unroll
        for (int dblk = 0; dblk < 4; ++dblk) {
            int d = dblk * 32 + qr;
            f32x16 a = acc[dblk];
            #pragma unroll
            for (int kb16 = 0; kb16 < 2; ++kb16) {
                int s = (2 * kb16 + hi) ^ ((d >> 1) & 3);
                bf16x8 vf = *(const bf16x8*)(Vt + d * 64 + s * 16);
                a = MFMA32(vf, pfr[kb16], a);
            }
            acc[dblk] = a;
        }
        __builtin_amdgcn_s_setprio(0);

        // tile end: t+1's loads done (only t+2's 4 may remain); all waves done with buf t
        asm volatile("s_waitcnt vmcnt(4)" ::: "memory");
        __builtin_amdgcn_s_barrier();

        // refill just-freed buffer with tile t+3
        if (t + 3 < 64) STAGE(t + 3, bufo);
        bufo = (bufo == 32768) ? 0 : bufo + 16384;
    }

    // epilogue: O[qrow][d], d = dblk*32 + rg*8 + 4*hi + q4; per-lane 1/l
    float linv = 1.f / lr;
    unsigned short* orow = O + (rowQ0 + qr) * 2048 + h * 128;
    #pragma unroll
    for (int dblk = 0; dblk < 4; ++dblk)
        #pragma unroll
        for (int rg = 0; rg < 4; ++rg) {
            float v0 = acc[dblk][rg * 4 + 0] * linv;
            float v1 = acc[dblk][rg * 4 + 1] * linv;
            float v2 = acc[dblk][rg * 4 + 2] * linv;
            float v3 = acc[dblk][rg * 4 + 3] * linv;
            uint2 o;
            o.x = packbf(v0, v1);
            o.y = packbf(v2, v3);
            *(uint2*)(orow + dblk * 32 + rg * 8 + hi * 4) = o;
        }
    #undef STAGE
}

// ---------------- host launch ----------------
extern "C" void kernel_launch(void* const* d_in, const int* in_sizes, int n_in,
                              void* d_out, int out_size, void* d_ws, size_t ws_size,
                              hipStream_t stream)
{
    (void)in_sizes; (void)n_in; (void)out_size; (void)ws_size;
    const float* x    = (const float*)d_in[0];
    const float* mask = (const float*)d_in[1];
    const float* Wq   = (const float*)d_in[2];
    const float* bq   = (const float*)d_in[3];
    const float* Wk   = (const float*)d_in[4];
    const float* bk   = (const float*)d_in[5];
    const float* Wv   = (const float*)d_in[6];
    const float* bv   = (const float*)d_in[7];
    const float* Wo   = (const float*)d_in[8];
    const float* bo   = (const float*)d_in[9];
    float* out = (float*)d_out;

    char* ws = (char*)d_ws;
    //  0..16  xb (bf16 x)
    // 16..40  Wqt,Wkt,Wvt (Ab reuses 16.., maskl2 reuses 32.. once dead)
    // 40..48  Wot (live to the end)
    // 48..64  Qb   64..80 Kb   80..96 Vtb
    unsigned short* xb  = (unsigned short*)(ws);
    unsigned short* Wqt = (unsigned short*)(ws + (16u << 20));
    unsigned short* Wkt = (unsigned short*)(ws + (24u << 20));
    unsigned short* Wvt = (unsigned short*)(ws + (32u << 20));
    unsigned short* Wot = (unsigned short*)(ws + (40u << 20));
    unsigned short* Qb  = (unsigned short*)(ws + (48u << 20));
    unsigned short* Kb  = (unsigned short*)(ws + (64u << 20));
    unsigned short* Vtb = (unsigned short*)(ws + (80u << 20));
    unsigned short* Ab  = (unsigned short*)(ws + (16u << 20));   // dead Wqt/Wkt
    float*          mkl = (float*)(ws + (32u << 20));            // dead Wvt

    cast_f32_bf16<<<2048, 256, 0, stream>>>(x, xb, MTOT * HHH);
    transpose_cast4<<<dim3(64, 64, 4), dim3(32, 8), 0, stream>>>(Wq, Wk, Wv, Wo, Wqt);

    gemm8_bf16<0><<<256, 512, 0, stream>>>(xb, Wqt, bq, Qb,  MTOT, HHH, HHH);
    gemm8_bf16<0><<<256, 512, 0, stream>>>(xb, Wkt, bk, Kb,  MTOT, HHH, HHH);
    gemm8_bf16<1><<<256, 512, 0, stream>>>(xb, Wvt, bv, Vtb, MTOT, HHH, HHH);

    scale_mask<<<(BB * SS) / 256, 256, 0, stream>>>(mask, mkl);   // after V GEMM (Wvt dead)
    attn_fwd<<<512, 256, 0, stream>>>(Qb, Kb, Vtb, mkl, Ab);

    gemm8_bf16<2><<<256, 512, 0, stream>>>(Ab, Wot, bo, out, MTOT, HHH, HHH);
}

// Round 10
// 276.242 us; speedup vs baseline: 1.4617x; 1.0122x over previous
//
#include <hip/hip_runtime.h>
#include <hip/hip_bf16.h>
#include <stdint.h>

// Problem constants
#define BB   2
#define SS   2048
#define HHH  2048
#define NHH  16
#define HDD  128
#define MTOT 4096   // BB*SS

typedef __bf16 bf16x8 __attribute__((ext_vector_type(8)));
typedef float  f32x4  __attribute__((ext_vector_type(4)));
typedef float  f32x16 __attribute__((ext_vector_type(16)));

#define MFMA16(a, b, c) __builtin_amdgcn_mfma_f32_16x16x32_bf16((a), (b), (c), 0, 0, 0)
#define MFMA32(a, b, c) __builtin_amdgcn_mfma_f32_32x32x16_bf16((a), (b), (c), 0, 0, 0)

__device__ __forceinline__ unsigned short f2bf(float f) {
    union { float f; unsigned u; } v; v.f = f;
    unsigned r = v.u + 0x7FFFu + ((v.u >> 16) & 1u);   // RNE
    return (unsigned short)(r >> 16);
}

__device__ __forceinline__ unsigned packbf(float a, float b) {
    union { __bf16 h[2]; unsigned u; } p;
    p.h[0] = (__bf16)a; p.h[1] = (__bf16)b;
    return p.u;
}

// v_permlane32_swap_b32: a' = [a.lo32, b.lo32], b' = [a.hi32, b.hi32]
__device__ __forceinline__ void pswap(unsigned &a, unsigned &b) {
    asm("v_permlane32_swap_b32 %0, %1" : "+v"(a), "+v"(b));
}

// cross-half (lane ^ 32) pair: returns {own-half view, other-half view}
__device__ __forceinline__ float2 xswap(float x) {
    unsigned a = __builtin_bit_cast(unsigned, x);
    unsigned b;
    asm("v_mov_b32 %0, %1" : "=v"(b) : "v"(a));   // force distinct register
    asm("v_permlane32_swap_b32 %0, %1" : "+v"(a), "+v"(b));
    return make_float2(__builtin_bit_cast(float, a), __builtin_bit_cast(float, b));
}

// async global->LDS, 16B per lane. LDS dest is wave-uniform base + lane*16.
__device__ __forceinline__ void gload16(const void* src, void* lds) {
    __builtin_amdgcn_global_load_lds(
        (__attribute__((address_space(1))) void*)src,
        (__attribute__((address_space(3))) void*)lds,
        16, 0, 0);
}

// ---------------- cast f32 -> bf16 (vectorized) ----------------
__global__ void cast_f32_bf16(const float* __restrict__ in,
                              unsigned short* __restrict__ out, int n) {
    int i = (blockIdx.x * blockDim.x + threadIdx.x) * 4;
    int stride = gridDim.x * blockDim.x * 4;
    for (; i < n; i += stride) {
        float4 v = *(const float4*)(in + i);
        ushort4 o;
        o.x = f2bf(v.x); o.y = f2bf(v.y); o.z = f2bf(v.z); o.w = f2bf(v.w);
        *(ushort4*)(out + i) = o;
    }
}

// ---------------- pre-scale mask by log2(e) ----------------
__global__ void scale_mask(const float* __restrict__ in, float* __restrict__ out) {
    int i = blockIdx.x * 256 + threadIdx.x;   // grid covers BB*SS
    out[i] = in[i] * 1.4426950408889634f;
}

// -------- transpose + cast all 4 weights: W (K x N f32) -> Wt (N x K bf16) --------
__global__ void transpose_cast4(const float* __restrict__ W0, const float* __restrict__ W1,
                                const float* __restrict__ W2, const float* __restrict__ W3,
                                unsigned short* __restrict__ out) {
    const float* in = blockIdx.z == 0 ? W0 : blockIdx.z == 1 ? W1 : blockIdx.z == 2 ? W2 : W3;
    unsigned short* o = out + (size_t)blockIdx.z * ((size_t)HHH * HHH);
    __shared__ float tile[32][33];
    int c0 = blockIdx.x * 32, r0 = blockIdx.y * 32;
    int tx = threadIdx.x, ty = threadIdx.y;   // (32, 8)
    #pragma unroll
    for (int i = 0; i < 32; i += 8)
        tile[ty + i][tx] = in[(size_t)(r0 + ty + i) * HHH + c0 + tx];
    __syncthreads();
    #pragma unroll
    for (int i = 0; i < 32; i += 8)
        o[(size_t)(c0 + ty + i) * HHH + r0 + tx] = f2bf(tile[tx][ty + i]);
}

// ---------------- 2-phase GEMM: C[M,N] = A[M,K] @ Bt[N,K]^T + bias ----------------
// BM=128, BN=256, BK=64. 8 waves (2M x 4N), per-wave 64x64 out, 512 threads.
// Triple-buffered LDS (3 x 48KB): 2-deep prefetch, counted vmcnt(6) at tile end.
// 2 phases/K-tile, 16 MFMA each; B fragments held in registers across phases.
template<int MODE>
__global__ __launch_bounds__(512, 2) void gemm8_bf16(
    const unsigned short* __restrict__ A,
    const unsigned short* __restrict__ Bt,
    const float* __restrict__ bias,
    void* __restrict__ Cout,
    int M, int N, int K)
{
    __shared__ __align__(16) unsigned char sm[147456];
    const int tid = threadIdx.x;
    const int wv = tid >> 6, ln = tid & 63;
    const int g = ln >> 4, r = ln & 15;
    const int wr = wv >> 2, wc = wv & 3;

    const int bid = blockIdx.x;
    const int lb = (bid & 7) * 32 + (bid >> 3);
    const int m0 = (lb & 31) * 128;
    const int n0 = (lb >> 5) * 256;

    unsigned srcA[2]; int ldsA[2];
    #pragma unroll
    for (int j = 0; j < 2; ++j) {
        int o = j * 8192 + tid * 16;
        int row = o >> 7;
        int lg = ((o >> 4) & 7) ^ (row & 7);
        srcA[j] = (unsigned)(m0 + row) * K + lg * 8;
        ldsA[j] = o;
    }
    unsigned srcB[4]; int ldsB[4];
    #pragma unroll
    for (int j = 0; j < 4; ++j) {
        int o = j * 8192 + tid * 16;
        int row = o >> 7;
        int lg = ((o >> 4) & 7) ^ (row & 7);
        srcB[j] = (unsigned)(n0 + row) * K + lg * 8;
        ldsB[j] = 16384 + o;
    }

    f32x4 acc[4][4];
    #pragma unroll
    for (int i = 0; i < 4; ++i)
        #pragma unroll
        for (int j = 0; j < 4; ++j)
            acc[i][j] = (f32x4){0.f, 0.f, 0.f, 0.f};

    const int NT = K >> 6;   // 32

    {
        unsigned char* b0 = sm;
        unsigned char* b1 = sm + 49152;
        #pragma unroll
        for (int j = 0; j < 2; ++j) gload16(A + srcA[j], b0 + ldsA[j]);
        #pragma unroll
        for (int j = 0; j < 4; ++j) gload16(Bt + srcB[j], b0 + ldsB[j]);
        #pragma unroll
        for (int j = 0; j < 2; ++j) gload16(A + srcA[j] + 64, b1 + ldsA[j]);
        #pragma unroll
        for (int j = 0; j < 4; ++j) gload16(Bt + srcB[j] + 64, b1 + ldsB[j]);
    }
    asm volatile("s_waitcnt vmcnt(6)" ::: "memory");
    __builtin_amdgcn_s_barrier();

    int csel = 0;
    int psel = 2;
    for (int t = 0; t < NT; ++t) {
        const unsigned char* Ab = sm + csel * 49152;
        const unsigned char* Bb = Ab + 16384;
        unsigned char* Pb = sm + psel * 49152;
        const bool pre = (t + 2 < NT);
        const int ko = (t + 2) * 64;

        bf16x8 af[2][2], bfr[4][2];
        #define LDA(mi, ks) (*(const bf16x8*)(Ab + (wr * 64 + (mi) * 16 + r) * 128 + \
                             ((((ks) << 2) + g) ^ ((wr * 64 + (mi) * 16 + r) & 7)) * 16))
        #define LDB(ni, ks) (*(const bf16x8*)(Bb + (wc * 64 + (ni) * 16 + r) * 128 + \
                             ((((ks) << 2) + g) ^ ((wc * 64 + (ni) * 16 + r) & 7)) * 16))

        // ---- phase A: A rows {0,1} x B cols {0..3}; stage B0,B1,B2
        af[0][0] = LDA(0, 0); af[0][1] = LDA(0, 1);
        af[1][0] = LDA(1, 0); af[1][1] = LDA(1, 1);
        #pragma unroll
        for (int ni = 0; ni < 4; ++ni) {
            bfr[ni][0] = LDB(ni, 0);
            bfr[ni][1] = LDB(ni, 1);
        }
        if (pre) { gload16(Bt + srcB[0] + ko, Pb + ldsB[0]);
                   gload16(Bt + srcB[1] + ko, Pb + ldsB[1]);
                   gload16(Bt + srcB[2] + ko, Pb + ldsB[2]); }
        __builtin_amdgcn_s_barrier();
        asm volatile("s_waitcnt lgkmcnt(0)" ::: "memory");
        __builtin_amdgcn_s_setprio(1);
        #pragma unroll
        for (int mi = 0; mi < 2; ++mi)
            #pragma unroll
            for (int ni = 0; ni < 4; ++ni)
                #pragma unroll
                for (int ks = 0; ks < 2; ++ks)
                    acc[mi][ni] = MFMA16(af[mi][ks], bfr[ni][ks], acc[mi][ni]);
        __builtin_amdgcn_s_setprio(0);
        __builtin_amdgcn_s_barrier();

        // ---- phase B: A rows {2,3} x B cols {0..3} (B held); stage B3,A0,A1
        af[0][0] = LDA(2, 0); af[0][1] = LDA(2, 1);
        af[1][0] = LDA(3, 0); af[1][1] = LDA(3, 1);
        if (pre) { gload16(Bt + srcB[3] + ko, Pb + ldsB[3]);
                   gload16(A + srcA[0] + ko, Pb + ldsA[0]);
                   gload16(A + srcA[1] + ko, Pb + ldsA[1]); }
        __builtin_amdgcn_s_barrier();
        asm volatile("s_waitcnt lgkmcnt(0)" ::: "memory");
        __builtin_amdgcn_s_setprio(1);
        #pragma unroll
        for (int mi = 0; mi < 2; ++mi)
            #pragma unroll
            for (int ni = 0; ni < 4; ++ni)
                #pragma unroll
                for (int ks = 0; ks < 2; ++ks)
                    acc[mi + 2][ni] = MFMA16(af[mi][ks], bfr[ni][ks], acc[mi + 2][ni]);
        __builtin_amdgcn_s_setprio(0);

        // tile end: tile t+1's 6 loads are the oldest outstanding
        if (pre) asm volatile("s_waitcnt vmcnt(6)" ::: "memory");
        else     asm volatile("s_waitcnt vmcnt(0)" ::: "memory");
        __builtin_amdgcn_s_barrier();

        csel = (csel == 2) ? 0 : csel + 1;
        psel = (psel == 2) ? 0 : psel + 1;
        #undef LDA
        #undef LDB
    }

    #pragma unroll
    for (int mt = 0; mt < 4; ++mt) {
        #pragma unroll
        for (int nt = 0; nt < 4; ++nt) {
            int col = n0 + wc * 64 + nt * 16 + r;
            float bvv = bias[col];
            f32x4 a = acc[mt][nt];
            int mrow = m0 + wr * 64 + mt * 16 + g * 4;
            if (MODE == 0) {
                #pragma unroll
                for (int q = 0; q < 4; ++q)
                    ((unsigned short*)Cout)[(size_t)(mrow + q) * N + col] = f2bf(a[q] + bvv);
            } else if (MODE == 2) {
                #pragma unroll
                for (int q = 0; q < 4; ++q)
                    ((float*)Cout)[(size_t)(mrow + q) * N + col] = a[q] + bvv;
            } else {
                int b = mrow >> 11, s0x = mrow & 2047;
                ushort4 o;
                o.x = f2bf(a[0] + bvv); o.y = f2bf(a[1] + bvv);
                o.z = f2bf(a[2] + bvv); o.w = f2bf(a[3] + bvv);
                *(ushort4*)((unsigned short*)Cout + ((size_t)(b * 2048 + col)) * 2048 + s0x) = o;
            }
        }
    }
}

// ---------------- flash attention: KVBLK=64, 2-buf counted pipeline, mask in LDS ----------------
// 512 blocks (2/CU), 4 waves x 32 q-rows. Dbuf {K[64][128], Vt[128][64]} (2 x 32KB)
// + mask row (8KB) = 72KB. Zero loop VMEM except 8 STAGE loads; stage-after-barrier
// + counted vmcnt(8) -> t+1's loads land a full tile (~4000 cy) before use.
__global__ __launch_bounds__(256, 2) void attn_fwd(
    const unsigned short* __restrict__ Q,
    const unsigned short* __restrict__ K,
    const unsigned short* __restrict__ V,
    const float* __restrict__ maskl2,   // mask * log2(e)
    unsigned short* __restrict__ O)
{
    __shared__ __align__(16) unsigned char sm[73728]; // 2 x 32KB KV bufs + 8KB mask @65536
    const int tid = threadIdx.x, wv = tid >> 6, ln = tid & 63;
    const int hi = ln >> 5, qr = ln & 31;

    // XCD-bijective swizzle (512 blocks = 8 XCD x 64): XCD owns 4 full heads
    const int bid = blockIdx.x;
    const int lb = (bid & 7) * 64 + (bid >> 3);
    const int qb = lb & 15;
    const int bh = lb >> 4;
    const int h = bh & 15, b = bh >> 4;

    const size_t rowQ0 = (size_t)(b * 2048 + qb * 128 + wv * 32);
    const float SCL2 = 0.08838834764831845f * 1.4426950408889634f; // scale*log2e

    // staging precompute (round-4/5 validated): K tile [64][128] (256B rows, 16 granules,
    // ^(row&7)); Vt tile [128][64] (128B rows, 8 granules, ^(d&7))
    unsigned srcK[4], srcV[4];
    int ldsK[4], ldsV[4];
    #pragma unroll
    for (int i = 0; i < 4; ++i) {
        int ch = wv * 4 + i;
        int o = ch * 1024 + ln * 16;
        { int row = o >> 8; int gl = ((o >> 4) & 15) ^ (row & 7);
          srcK[i] = (unsigned)((b * 2048 + row) * 2048 + h * 128 + gl * 8);
          ldsK[i] = o; }
        { int d = o >> 7; int gl = ((o >> 4) & 7) ^ (d & 7);
          srcV[i] = (unsigned)((b * 2048 + h * 128 + d) * 2048 + gl * 8);
          ldsV[i] = 16384 + o; }
    }

    #define STAGE(t, base) { \
        _Pragma("unroll") \
        for (int i = 0; i < 4; ++i) { \
            gload16(K + srcK[i] + (unsigned)(t) * (64u * 2048u), sm + (base) + ldsK[i]); \
            gload16(V + srcV[i] + (unsigned)(t) * 64u, sm + (base) + ldsV[i]); \
        } }

    // prologue: mask row -> LDS first (oldest), then tiles 0,1
    #pragma unroll
    for (int i = 0; i < 2; ++i)
        gload16(maskl2 + b * 2048 + wv * 512 + i * 256 + ln * 4,
                sm + 65536 + wv * 2048 + i * 1024);
    STAGE(0, 0); STAGE(1, 32768);

    // Q fragments (B-operand): col = qr, k = hi*8+j, 8 k-steps of 16
    bf16x8 qf[8];
    #pragma unroll
    for (int ks = 0; ks < 8; ++ks)
        qf[ks] = *(const bf16x8*)(Q + (rowQ0 + qr) * 2048 + h * 128 + ks * 16 + hi * 8);

    f32x16 acc[4];
    #pragma unroll
    for (int i = 0; i < 4; ++i)
        #pragma unroll
        for (int j = 0; j < 16; ++j)
            acc[i][j] = 0.f;
    float mr = -3.0e38f, lr = 0.f;   // per-lane: q-row = qr

    const float* ml = (const float*)(sm + 65536);

    // of 18 outstanding (2 mask + 8 + 8), wait until only 8 (tile 1) remain
    asm volatile("s_waitcnt vmcnt(8)" ::: "memory");
    __builtin_amdgcn_s_barrier();

    for (int t = 0; t < 32; ++t) {
        const unsigned char* Kt = sm + (t & 1) * 32768;
        const unsigned char* Vt = Kt + 16384;

        // mask values from LDS: key = t*64 + kb2*32 + rg*8 + hi*4 + q4 (pre-scaled)
        f32x4 mk[2][4];
        #pragma unroll
        for (int kb2 = 0; kb2 < 2; ++kb2)
            #pragma unroll
            for (int rg = 0; rg < 4; ++rg)
                mk[kb2][rg] = *(const f32x4*)(ml + t * 64 + kb2 * 32 + rg * 8 + hi * 4);

        // S^T = K Q^T : two independent 8-deep chains (keys 0-31 / 32-63)
        f32x16 sf0, sf1;
        #pragma unroll
        for (int j = 0; j < 16; ++j) { sf0[j] = 0.f; sf1[j] = 0.f; }
        __builtin_amdgcn_s_setprio(1);
        #pragma unroll
        for (int ks = 0; ks < 8; ++ks) {
            int row0 = qr, row1 = 32 + qr;
            int s0 = ((2 * ks + hi) ^ (row0 & 7));
            int s1 = ((2 * ks + hi) ^ (row1 & 7));
            bf16x8 kf0 = *(const bf16x8*)(Kt + row0 * 256 + s0 * 16);
            bf16x8 kf1 = *(const bf16x8*)(Kt + row1 * 256 + s1 * 16);
            sf0 = MFMA32(kf0, qf[ks], sf0);
            sf1 = MFMA32(kf1, qf[ks], sf1);
        }
        __builtin_amdgcn_s_setprio(0);

        // scale + mask (log2 domain; mask pre-scaled)
        float sv[2][16];
        #pragma unroll
        for (int reg = 0; reg < 16; ++reg) {
            sv[0][reg] = sf0[reg] * SCL2 + mk[0][reg >> 2][reg & 3];
            sv[1][reg] = sf1[reg] * SCL2 + mk[1][reg >> 2][reg & 3];
        }

        // row max: balanced tree over 32 in-lane values, then cross-half permlane
        float mx[8];
        #pragma unroll
        for (int j = 0; j < 8; ++j)
            mx[j] = fmaxf(fmaxf(sv[0][2*j], sv[0][2*j+1]),
                          fmaxf(sv[1][2*j], sv[1][2*j+1]));
        float m01 = fmaxf(fmaxf(fmaxf(mx[0], mx[1]), fmaxf(mx[2], mx[3])),
                          fmaxf(fmaxf(mx[4], mx[5]), fmaxf(mx[6], mx[7])));
        float2 mp = xswap(m01);
        float mt = fmaxf(mp.x, mp.y);

        // defer-max
        float alpha = 1.f;
        int allskip = __all(mt <= mr + 8.f);
        if (!allskip) {
            float nm = fmaxf(mr, mt);
            alpha = __builtin_amdgcn_exp2f(mr - nm);
            mr = nm;
            #pragma unroll
            for (int dblk = 0; dblk < 4; ++dblk)
                #pragma unroll
                for (int reg = 0; reg < 16; ++reg)
                    acc[dblk][reg] *= alpha;
        }

        // P = exp2(S - m), row sum (4 partials), cross-half permlane
        float s0 = 0.f, s1 = 0.f, s2 = 0.f, s3 = 0.f;
        #pragma unroll
        for (int kb2 = 0; kb2 < 2; ++kb2)
            #pragma unroll
            for (int reg = 0; reg < 16; reg += 4) {
                float p0 = __builtin_amdgcn_exp2f(sv[kb2][reg + 0] - mr);
                float p1 = __builtin_amdgcn_exp2f(sv[kb2][reg + 1] - mr);
                float p2 = __builtin_amdgcn_exp2f(sv[kb2][reg + 2] - mr);
                float p3 = __builtin_amdgcn_exp2f(sv[kb2][reg + 3] - mr);
                sv[kb2][reg + 0] = p0; sv[kb2][reg + 1] = p1;
                sv[kb2][reg + 2] = p2; sv[kb2][reg + 3] = p3;
                s0 += p0; s1 += p1; s2 += p2; s3 += p3;
            }
        float rsl = (s0 + s1) + (s2 + s3);
        float2 rp = xswap(rsl);
        float rs = rp.x + rp.y;
        lr = lr * alpha + rs;

        // P -> PV B-fragments via permlane32_swap (kb16 in {0..3})
        bf16x8 pfr[4];
        #pragma unroll
        for (int kb16 = 0; kb16 < 4; ++kb16) {
            const int kb2 = kb16 >> 1, i2 = kb16 & 1;
            float* pv = sv[kb2];
            unsigned W00 = packbf(pv[(2*i2+0)*4 + 0], pv[(2*i2+0)*4 + 1]);
            unsigned W01 = packbf(pv[(2*i2+0)*4 + 2], pv[(2*i2+0)*4 + 3]);
            unsigned W10 = packbf(pv[(2*i2+1)*4 + 0], pv[(2*i2+1)*4 + 1]);
            unsigned W11 = packbf(pv[(2*i2+1)*4 + 2], pv[(2*i2+1)*4 + 3]);
            pswap(W00, W10);
            pswap(W01, W11);
            union { unsigned w[4]; bf16x8 v; } u;
            u.w[0] = W00; u.w[1] = W01; u.w[2] = W10; u.w[3] = W11;
            pfr[kb16] = u.v;
        }

        // O^T += V^T P^T
        __builtin_amdgcn_s_setprio(1);
        #pragma unroll
        for (int dblk = 0; dblk < 4; ++dblk) {
            int d = dblk * 32 + qr;
            f32x16 a = acc[dblk];
            #pragma unroll
            for (int kb16 = 0; kb16 < 4; ++kb16) {
                int s = ((2 * kb16 + hi) ^ (d & 7));
                bf16x8 vf = *(const bf16x8*)(Vt + d * 128 + s * 16);
                a = MFMA32(vf, pfr[kb16], a);
            }
            acc[dblk] = a;
        }
        __builtin_amdgcn_s_setprio(0);

        // tile end: all waves done reading buf t&1, refill it with t+2, then
        // counted wait -> t+1's 8 loads (oldest) complete; t+2's 8 stay in flight
        __builtin_amdgcn_s_barrier();
        if (t + 2 < 32) {
            STAGE(t + 2, (t & 1) * 32768);
            asm volatile("s_waitcnt vmcnt(8)" ::: "memory");
        } else {
            asm volatile("s_waitcnt vmcnt(0)" ::: "memory");
        }
        __builtin_amdgcn_s_barrier();
    }

    // epilogue: O[qrow][d], d = dblk*32 + rg*8 + 4*hi + q4; per-lane 1/l
    float linv = 1.f / lr;
    unsigned short* orow = O + (rowQ0 + qr) * 2048 + h * 128;
    #pragma unroll
    for (int dblk = 0; dblk < 4; ++dblk)
        #pragma unroll
        for (int rg = 0; rg < 4; ++rg) {
            float v0 = acc[dblk][rg * 4 + 0] * linv;
            float v1 = acc[dblk][rg * 4 + 1] * linv;
            float v2 = acc[dblk][rg * 4 + 2] * linv;
            float v3 = acc[dblk][rg * 4 + 3] * linv;
            uint2 o;
            o.x = packbf(v0, v1);
            o.y = packbf(v2, v3);
            *(uint2*)(orow + dblk * 32 + rg * 8 + hi * 4) = o;
        }
    #undef STAGE
}

// ---------------- host launch ----------------
extern "C" void kernel_launch(void* const* d_in, const int* in_sizes, int n_in,
                              void* d_out, int out_size, void* d_ws, size_t ws_size,
                              hipStream_t stream)
{
    (void)in_sizes; (void)n_in; (void)out_size; (void)ws_size;
    const float* x    = (const float*)d_in[0];
    const float* mask = (const float*)d_in[1];
    const float* Wq   = (const float*)d_in[2];
    const float* bq   = (const float*)d_in[3];
    const float* Wk   = (const float*)d_in[4];
    const float* bk   = (const float*)d_in[5];
    const float* Wv   = (const float*)d_in[6];
    const float* bv   = (const float*)d_in[7];
    const float* Wo   = (const float*)d_in[8];
    const float* bo   = (const float*)d_in[9];
    float* out = (float*)d_out;

    char* ws = (char*)d_ws;
    //  0..16  xb (bf16 x)
    // 16..40  Wqt,Wkt,Wvt (Ab reuses 16.., maskl2 reuses 32.. once dead)
    // 40..48  Wot (live to the end)
    // 48..64  Qb   64..80 Kb   80..96 Vtb
    unsigned short* xb  = (unsigned short*)(ws);
    unsigned short* Wqt = (unsigned short*)(ws + (16u << 20));
    unsigned short* Wkt = (unsigned short*)(ws + (24u << 20));
    unsigned short* Wvt = (unsigned short*)(ws + (32u << 20));
    unsigned short* Wot = (unsigned short*)(ws + (40u << 20));
    unsigned short* Qb  = (unsigned short*)(ws + (48u << 20));
    unsigned short* Kb  = (unsigned short*)(ws + (64u << 20));
    unsigned short* Vtb = (unsigned short*)(ws + (80u << 20));
    unsigned short* Ab  = (unsigned short*)(ws + (16u << 20));   // dead Wqt/Wkt
    float*          mkl = (float*)(ws + (32u << 20));            // dead Wvt

    cast_f32_bf16<<<2048, 256, 0, stream>>>(x, xb, MTOT * HHH);
    transpose_cast4<<<dim3(64, 64, 4), dim3(32, 8), 0, stream>>>(Wq, Wk, Wv, Wo, Wqt);

    gemm8_bf16<0><<<256, 512, 0, stream>>>(xb, Wqt, bq, Qb,  MTOT, HHH, HHH);
    gemm8_bf16<0><<<256, 512, 0, stream>>>(xb, Wkt, bk, Kb,  MTOT, HHH, HHH);
    gemm8_bf16<1><<<256, 512, 0, stream>>>(xb, Wvt, bv, Vtb, MTOT, HHH, HHH);

    scale_mask<<<(BB * SS) / 256, 256, 0, stream>>>(mask, mkl);   // after V GEMM (Wvt dead)
    attn_fwd<<<512, 256, 0, stream>>>(Qb, Kb, Vtb, mkl, Ab);

    gemm8_bf16<2><<<256, 512, 0, stream>>>(Ab, Wot, bo, out, MTOT, HHH, HHH);
}

// Round 11
// 275.820 us; speedup vs baseline: 1.4639x; 1.0015x over previous
//
#include <hip/hip_runtime.h>
#include <hip/hip_bf16.h>
#include <stdint.h>

// Problem constants
#define BB   2
#define SS   2048
#define HHH  2048
#define NHH  16
#define HDD  128
#define MTOT 4096   // BB*SS

typedef __bf16 bf16x8 __attribute__((ext_vector_type(8)));
typedef float  f32x4  __attribute__((ext_vector_type(4)));
typedef float  f32x16 __attribute__((ext_vector_type(16)));

#define MFMA16(a, b, c) __builtin_amdgcn_mfma_f32_16x16x32_bf16((a), (b), (c), 0, 0, 0)
#define MFMA32(a, b, c) __builtin_amdgcn_mfma_f32_32x32x16_bf16((a), (b), (c), 0, 0, 0)

__device__ __forceinline__ unsigned short f2bf(float f) {
    union { float f; unsigned u; } v; v.f = f;
    unsigned r = v.u + 0x7FFFu + ((v.u >> 16) & 1u);   // RNE
    return (unsigned short)(r >> 16);
}

__device__ __forceinline__ unsigned packbf(float a, float b) {
    union { __bf16 h[2]; unsigned u; } p;
    p.h[0] = (__bf16)a; p.h[1] = (__bf16)b;
    return p.u;
}

// v_permlane32_swap_b32: a' = [a.lo32, b.lo32], b' = [a.hi32, b.hi32]
__device__ __forceinline__ void pswap(unsigned &a, unsigned &b) {
    asm("v_permlane32_swap_b32 %0, %1" : "+v"(a), "+v"(b));
}

// cross-half (lane ^ 32) pair: returns {own-half view, other-half view}
__device__ __forceinline__ float2 xswap(float x) {
    unsigned a = __builtin_bit_cast(unsigned, x);
    unsigned b;
    asm("v_mov_b32 %0, %1" : "=v"(b) : "v"(a));   // force distinct register
    asm("v_permlane32_swap_b32 %0, %1" : "+v"(a), "+v"(b));
    return make_float2(__builtin_bit_cast(float, a), __builtin_bit_cast(float, b));
}

// async global->LDS, 16B per lane. LDS dest is wave-uniform base + lane*16.
__device__ __forceinline__ void gload16(const void* src, void* lds) {
    __builtin_amdgcn_global_load_lds(
        (__attribute__((address_space(1))) void*)src,
        (__attribute__((address_space(3))) void*)lds,
        16, 0, 0);
}

// ---------------- cast f32 -> bf16 (vectorized) ----------------
__global__ void cast_f32_bf16(const float* __restrict__ in,
                              unsigned short* __restrict__ out, int n) {
    int i = (blockIdx.x * blockDim.x + threadIdx.x) * 4;
    int stride = gridDim.x * blockDim.x * 4;
    for (; i < n; i += stride) {
        float4 v = *(const float4*)(in + i);
        ushort4 o;
        o.x = f2bf(v.x); o.y = f2bf(v.y); o.z = f2bf(v.z); o.w = f2bf(v.w);
        *(ushort4*)(out + i) = o;
    }
}

// ---------------- pre-scale mask by log2(e) ----------------
__global__ void scale_mask(const float* __restrict__ in, float* __restrict__ out) {
    int i = blockIdx.x * 256 + threadIdx.x;   // grid covers BB*SS
    out[i] = in[i] * 1.4426950408889634f;
}

// -------- transpose + cast all 4 weights: W (K x N f32) -> Wt (N x K bf16) --------
__global__ void transpose_cast4(const float* __restrict__ W0, const float* __restrict__ W1,
                                const float* __restrict__ W2, const float* __restrict__ W3,
                                unsigned short* __restrict__ out) {
    const float* in = blockIdx.z == 0 ? W0 : blockIdx.z == 1 ? W1 : blockIdx.z == 2 ? W2 : W3;
    unsigned short* o = out + (size_t)blockIdx.z * ((size_t)HHH * HHH);
    __shared__ float tile[32][33];
    int c0 = blockIdx.x * 32, r0 = blockIdx.y * 32;
    int tx = threadIdx.x, ty = threadIdx.y;   // (32, 8)
    #pragma unroll
    for (int i = 0; i < 32; i += 8)
        tile[ty + i][tx] = in[(size_t)(r0 + ty + i) * HHH + c0 + tx];
    __syncthreads();
    #pragma unroll
    for (int i = 0; i < 32; i += 8)
        o[(size_t)(c0 + ty + i) * HHH + r0 + tx] = f2bf(tile[tx][ty + i]);
}

// ================= shared 2-phase GEMM core (BM=128, BN=256, BK=64) =================
// 8 waves (2M x 4N), per-wave 64x64, 512 threads, 3x48KB LDS, counted vmcnt(6).
// Computes acc[4][4]; staging/compute identical to the round-9-validated gemm8.
#define GEMM_CORE(A_, Bt_, K_, m0_, n0_)                                              \
    unsigned srcA[2]; int ldsA[2];                                                    \
    _Pragma("unroll")                                                                 \
    for (int j = 0; j < 2; ++j) {                                                     \
        int o = j * 8192 + tid * 16;                                                  \
        int row = o >> 7;                                                             \
        int lg = ((o >> 4) & 7) ^ (row & 7);                                          \
        srcA[j] = (unsigned)(m0_ + row) * K_ + lg * 8;                                \
        ldsA[j] = o;                                                                  \
    }                                                                                 \
    unsigned srcB[4]; int ldsB[4];                                                    \
    _Pragma("unroll")                                                                 \
    for (int j = 0; j < 4; ++j) {                                                     \
        int o = j * 8192 + tid * 16;                                                  \
        int row = o >> 7;                                                             \
        int lg = ((o >> 4) & 7) ^ (row & 7);                                          \
        srcB[j] = (unsigned)(n0_ + row) * K_ + lg * 8;                                \
        ldsB[j] = 16384 + o;                                                          \
    }                                                                                 \
    f32x4 acc[4][4];                                                                  \
    _Pragma("unroll")                                                                 \
    for (int i = 0; i < 4; ++i)                                                       \
        _Pragma("unroll")                                                             \
        for (int j = 0; j < 4; ++j)                                                   \
            acc[i][j] = (f32x4){0.f, 0.f, 0.f, 0.f};                                  \
    const int NT = K_ >> 6;                                                           \
    {                                                                                 \
        unsigned char* b0 = sm;                                                       \
        unsigned char* b1 = sm + 49152;                                               \
        _Pragma("unroll")                                                             \
        for (int j = 0; j < 2; ++j) gload16(A_ + srcA[j], b0 + ldsA[j]);              \
        _Pragma("unroll")                                                             \
        for (int j = 0; j < 4; ++j) gload16(Bt_ + srcB[j], b0 + ldsB[j]);             \
        _Pragma("unroll")                                                             \
        for (int j = 0; j < 2; ++j) gload16(A_ + srcA[j] + 64, b1 + ldsA[j]);         \
        _Pragma("unroll")                                                             \
        for (int j = 0; j < 4; ++j) gload16(Bt_ + srcB[j] + 64, b1 + ldsB[j]);        \
    }                                                                                 \
    asm volatile("s_waitcnt vmcnt(6)" ::: "memory");                                  \
    __builtin_amdgcn_s_barrier();                                                     \
    int csel = 0, psel = 2;                                                           \
    for (int t = 0; t < NT; ++t) {                                                    \
        const unsigned char* Ab = sm + csel * 49152;                                  \
        const unsigned char* Bb = Ab + 16384;                                         \
        unsigned char* Pb = sm + psel * 49152;                                        \
        const bool pre = (t + 2 < NT);                                                \
        const int ko = (t + 2) * 64;                                                  \
        bf16x8 af[2][2], bfr[4][2];                                                   \
        af[0][0] = LDA(0, 0); af[0][1] = LDA(0, 1);                                   \
        af[1][0] = LDA(1, 0); af[1][1] = LDA(1, 1);                                   \
        _Pragma("unroll")                                                             \
        for (int ni = 0; ni < 4; ++ni) { bfr[ni][0] = LDB(ni, 0); bfr[ni][1] = LDB(ni, 1); } \
        if (pre) { gload16(Bt_ + srcB[0] + ko, Pb + ldsB[0]);                         \
                   gload16(Bt_ + srcB[1] + ko, Pb + ldsB[1]);                         \
                   gload16(Bt_ + srcB[2] + ko, Pb + ldsB[2]); }                       \
        __builtin_amdgcn_s_barrier();                                                 \
        asm volatile("s_waitcnt lgkmcnt(0)" ::: "memory");                            \
        __builtin_amdgcn_s_setprio(1);                                                \
        _Pragma("unroll")                                                             \
        for (int mi = 0; mi < 2; ++mi)                                                \
            _Pragma("unroll")                                                         \
            for (int ni = 0; ni < 4; ++ni)                                            \
                _Pragma("unroll")                                                     \
                for (int ks = 0; ks < 2; ++ks)                                        \
                    acc[mi][ni] = MFMA16(af[mi][ks], bfr[ni][ks], acc[mi][ni]);       \
        __builtin_amdgcn_s_setprio(0);                                                \
        __builtin_amdgcn_s_barrier();                                                 \
        af[0][0] = LDA(2, 0); af[0][1] = LDA(2, 1);                                   \
        af[1][0] = LDA(3, 0); af[1][1] = LDA(3, 1);                                   \
        if (pre) { gload16(Bt_ + srcB[3] + ko, Pb + ldsB[3]);                         \
                   gload16(A_ + srcA[0] + ko, Pb + ldsA[0]);                          \
                   gload16(A_ + srcA[1] + ko, Pb + ldsA[1]); }                        \
        __builtin_amdgcn_s_barrier();                                                 \
        asm volatile("s_waitcnt lgkmcnt(0)" ::: "memory");                            \
        __builtin_amdgcn_s_setprio(1);                                                \
        _Pragma("unroll")                                                             \
        for (int mi = 0; mi < 2; ++mi)                                                \
            _Pragma("unroll")                                                         \
            for (int ni = 0; ni < 4; ++ni)                                            \
                _Pragma("unroll")                                                     \
                for (int ks = 0; ks < 2; ++ks)                                        \
                    acc[mi + 2][ni] = MFMA16(af[mi][ks], bfr[ni][ks], acc[mi + 2][ni]); \
        __builtin_amdgcn_s_setprio(0);                                                \
        if (pre) asm volatile("s_waitcnt vmcnt(6)" ::: "memory");                     \
        else     asm volatile("s_waitcnt vmcnt(0)" ::: "memory");                     \
        __builtin_amdgcn_s_barrier();                                                 \
        csel = (csel == 2) ? 0 : csel + 1;                                            \
        psel = (psel == 2) ? 0 : psel + 1;                                            \
    }

#define LDA(mi, ks) (*(const bf16x8*)(Ab + (wr * 64 + (mi) * 16 + r) * 128 + \
                     ((((ks) << 2) + g) ^ ((wr * 64 + (mi) * 16 + r) & 7)) * 16))
#define LDB(ni, ks) (*(const bf16x8*)(Bb + (wc * 64 + (ni) * 16 + r) * 128 + \
                     ((((ks) << 2) + g) ^ ((wc * 64 + (ni) * 16 + r) & 7)) * 16))

// ---------------- fused QKV GEMM: [Q|K|Vt] = x @ [Wqt|Wkt|Wvt]^T + bias ----------------
// N = 6144 (3 x 2048), grid 768 = 8 XCD x 96 (bijective). Region per block: n0>>11.
__global__ __launch_bounds__(512, 2) void gemmQKV(
    const unsigned short* __restrict__ A,
    const unsigned short* __restrict__ Bt,     // Wqt|Wkt|Wvt contiguous, 6144 x 2048
    const float* __restrict__ bq,
    const float* __restrict__ bk,
    const float* __restrict__ bv,
    unsigned short* __restrict__ Qb,
    unsigned short* __restrict__ Kb,
    unsigned short* __restrict__ Vtb)
{
    __shared__ __align__(16) unsigned char sm[147456];
    const int tid = threadIdx.x;
    const int wv = tid >> 6, ln = tid & 63;
    const int g = ln >> 4, r = ln & 15;
    const int wr = wv >> 2, wc = wv & 3;

    const int bid = blockIdx.x;
    const int lb = (bid & 7) * 96 + (bid >> 3);
    const int m0 = (lb & 31) * 128;
    const int n0 = (lb >> 5) * 256;
    const int K = HHH;

    GEMM_CORE(A, Bt, K, m0, n0)

    const int region = n0 >> 11;   // 0=Q, 1=K, 2=V (block-uniform)
    const float* bp = region == 0 ? bq : (region == 1 ? bk : bv);
    unsigned short* outp = region == 0 ? Qb : Kb;
    #pragma unroll
    for (int mt = 0; mt < 4; ++mt) {
        #pragma unroll
        for (int nt = 0; nt < 4; ++nt) {
            int col = n0 + wc * 64 + nt * 16 + r;
            int lcol = col & 2047;
            float bvv = bp[lcol];
            f32x4 a = acc[mt][nt];
            int mrow = m0 + wr * 64 + mt * 16 + g * 4;
            if (region < 2) {
                #pragma unroll
                for (int q = 0; q < 4; ++q)
                    outp[(size_t)(mrow + q) * 2048 + lcol] = f2bf(a[q] + bvv);
            } else {
                int b = mrow >> 11, s0x = mrow & 2047;
                ushort4 o;
                o.x = f2bf(a[0] + bvv); o.y = f2bf(a[1] + bvv);
                o.z = f2bf(a[2] + bvv); o.w = f2bf(a[3] + bvv);
                *(ushort4*)(Vtb + ((size_t)(b * 2048 + lcol)) * 2048 + s0x) = o;
            }
        }
    }
}

// ---------------- Wo GEMM (f32 out) ----------------
__global__ __launch_bounds__(512, 2) void gemmO(
    const unsigned short* __restrict__ A,
    const unsigned short* __restrict__ Bt,
    const float* __restrict__ bias,
    float* __restrict__ Cout)
{
    __shared__ __align__(16) unsigned char sm[147456];
    const int tid = threadIdx.x;
    const int wv = tid >> 6, ln = tid & 63;
    const int g = ln >> 4, r = ln & 15;
    const int wr = wv >> 2, wc = wv & 3;

    const int bid = blockIdx.x;
    const int lb = (bid & 7) * 32 + (bid >> 3);
    const int m0 = (lb & 31) * 128;
    const int n0 = (lb >> 5) * 256;
    const int K = HHH;

    GEMM_CORE(A, Bt, K, m0, n0)

    #pragma unroll
    for (int mt = 0; mt < 4; ++mt) {
        #pragma unroll
        for (int nt = 0; nt < 4; ++nt) {
            int col = n0 + wc * 64 + nt * 16 + r;
            float bvv = bias[col];
            f32x4 a = acc[mt][nt];
            int mrow = m0 + wr * 64 + mt * 16 + g * 4;
            #pragma unroll
            for (int q = 0; q < 4; ++q)
                Cout[(size_t)(mrow + q) * 2048 + col] = a[q] + bvv;
        }
    }
}

#undef LDA
#undef LDB

// ---------------- flash attention: KVBLK=32, 3-buf, QK^T pipelined one tile ahead ----
// 512 blocks (2/CU), 4 waves x 32 q-rows. Body t: QK(t+1) MFMA interleaves with
// softmax(t) VALU (independent pipes, one basic block), then PV(t).
// Counted vmcnt(4) guarantees tile t+2 resident at body t+1 start.
__global__ __launch_bounds__(256, 2) void attn_fwd(
    const unsigned short* __restrict__ Q,
    const unsigned short* __restrict__ K,
    const unsigned short* __restrict__ V,
    const float* __restrict__ maskl2,   // mask * log2(e)
    unsigned short* __restrict__ O)
{
    __shared__ __align__(16) unsigned char sm[57344]; // 3 x 16KB KV bufs + 8KB mask @49152
    const int tid = threadIdx.x, wv = tid >> 6, ln = tid & 63;
    const int hi = ln >> 5, qr = ln & 31;

    // XCD-bijective swizzle (512 blocks = 8 XCD x 64): XCD owns 4 full heads
    const int bid = blockIdx.x;
    const int lb = (bid & 7) * 64 + (bid >> 3);
    const int qb = lb & 15;
    const int bh = lb >> 4;
    const int h = bh & 15, b = bh >> 4;

    const size_t rowQ0 = (size_t)(b * 2048 + qb * 128 + wv * 32);
    const float SCL2 = 0.08838834764831845f * 1.4426950408889634f; // scale*log2e

    // Q fragments FIRST (oldest vmem) so the compiler's qf-wait doesn't drain staging
    bf16x8 qf[8];
    #pragma unroll
    for (int ks = 0; ks < 8; ++ks)
        qf[ks] = *(const bf16x8*)(Q + (rowQ0 + qr) * 2048 + h * 128 + ks * 16 + hi * 8);

    // staging precompute: K tile [32][128] (256B rows, 16 granules, ^(row&7));
    //                     Vt tile [128][32] (64B rows, 4 granules, ^((d>>1)&3))
    unsigned srcK[2], srcV[2];
    int ldsK[2], ldsV[2];
    #pragma unroll
    for (int i = 0; i < 2; ++i) {
        int ch = wv * 2 + i;
        int o = ch * 1024 + ln * 16;
        { int row = o >> 8; int gl = ((o >> 4) & 15) ^ (row & 7);
          srcK[i] = (unsigned)((b * 2048 + row) * 2048 + h * 128 + gl * 8);
          ldsK[i] = o; }
        { int d = o >> 6; int gl = ((o >> 4) & 3) ^ ((d >> 1) & 3);
          srcV[i] = (unsigned)((b * 2048 + h * 128 + d) * 2048 + gl * 8);
          ldsV[i] = 8192 + o; }
    }

    #define STAGE(t, base) { \
        _Pragma("unroll") \
        for (int i = 0; i < 2; ++i) { \
            gload16(K + srcK[i] + (unsigned)(t) * (32u * 2048u), sm + (base) + ldsK[i]); \
            gload16(V + srcV[i] + (unsigned)(t) * 32u, sm + (base) + ldsV[i]); \
        } }

    // prologue: mask row -> LDS, then tiles 0,1,2
    #pragma unroll
    for (int i = 0; i < 2; ++i)
        gload16(maskl2 + b * 2048 + wv * 512 + i * 256 + ln * 4,
                sm + 49152 + wv * 2048 + i * 1024);
    STAGE(0, 0); STAGE(1, 16384); STAGE(2, 32768);

    f32x16 acc[4];
    #pragma unroll
    for (int i = 0; i < 4; ++i)
        #pragma unroll
        for (int j = 0; j < 16; ++j)
            acc[i][j] = 0.f;
    float mr = -3.0e38f, lr = 0.f;   // per-lane: q-row = qr

    const float* ml = (const float*)(sm + 49152);

    // wait: all but tile2's 4 loads done (qf, mask, tiles 0,1 landed)
    asm volatile("s_waitcnt vmcnt(4)" ::: "memory");
    __builtin_amdgcn_s_barrier();

    // prologue QK(0) -> sv
    float sv[16];
    {
        f32x16 sfA, sfB;
        #pragma unroll
        for (int j = 0; j < 16; ++j) { sfA[j] = 0.f; sfB[j] = 0.f; }
        #pragma unroll
        for (int ks = 0; ks < 4; ++ks) {
            int s0 = (2 * ks + hi) ^ (qr & 7);
            bf16x8 kf = *(const bf16x8*)(sm + qr * 256 + s0 * 16);
            sfA = MFMA32(kf, qf[ks], sfA);
        }
        #pragma unroll
        for (int ks = 4; ks < 8; ++ks) {
            int s0 = (2 * ks + hi) ^ (qr & 7);
            bf16x8 kf = *(const bf16x8*)(sm + qr * 256 + s0 * 16);
            sfB = MFMA32(kf, qf[ks], sfB);
        }
        #pragma unroll
        for (int reg = 0; reg < 16; ++reg)
            sv[reg] = (sfA[reg] + sfB[reg]) * SCL2 + ml[(reg >> 2) * 8 + hi * 4 + (reg & 3)];
    }

    int base0 = 0;   // byte offset of buf t%3
    for (int t = 0; t < 63; ++t) {
        const int baseN = (base0 == 32768) ? 0 : base0 + 16384;   // buf (t+1)%3
        const unsigned char* Vt = sm + base0 + 8192;
        const unsigned char* Kn = sm + baseN;

        // ---- QK(t+1): MFMA + ds_read, independent of softmax below (same block)
        f32x16 sfA, sfB;
        #pragma unroll
        for (int j = 0; j < 16; ++j) { sfA[j] = 0.f; sfB[j] = 0.f; }
        __builtin_amdgcn_s_setprio(1);
        #pragma unroll
        for (int ks = 0; ks < 4; ++ks) {
            int s0 = (2 * ks + hi) ^ (qr & 7);
            bf16x8 kf = *(const bf16x8*)(Kn + qr * 256 + s0 * 16);
            sfA = MFMA32(kf, qf[ks], sfA);
        }
        #pragma unroll
        for (int ks = 4; ks < 8; ++ks) {
            int s0 = (2 * ks + hi) ^ (qr & 7);
            bf16x8 kf = *(const bf16x8*)(Kn + qr * 256 + s0 * 16);
            sfB = MFMA32(kf, qf[ks], sfB);
        }
        __builtin_amdgcn_s_setprio(0);

        // ---- softmax(t) on sv (VALU; scheduler interleaves with QK above)
        float mx[8];
        #pragma unroll
        for (int j = 0; j < 8; ++j)
            mx[j] = fmaxf(sv[2 * j], sv[2 * j + 1]);
        float m01 = fmaxf(fmaxf(fmaxf(mx[0], mx[1]), fmaxf(mx[2], mx[3])),
                          fmaxf(fmaxf(mx[4], mx[5]), fmaxf(mx[6], mx[7])));
        float2 mp = xswap(m01);
        float mt = fmaxf(mp.x, mp.y);

        float alpha = 1.f;
        int allskip = __all(mt <= mr + 8.f);
        if (!allskip) {
            float nm = fmaxf(mr, mt);
            alpha = __builtin_amdgcn_exp2f(mr - nm);
            mr = nm;
            #pragma unroll
            for (int dblk = 0; dblk < 4; ++dblk)
                #pragma unroll
                for (int reg = 0; reg < 16; ++reg)
                    acc[dblk][reg] *= alpha;
        }

        float s0 = 0.f, s1 = 0.f, s2 = 0.f, s3 = 0.f;
        #pragma unroll
        for (int reg = 0; reg < 16; reg += 4) {
            float p0 = __builtin_amdgcn_exp2f(sv[reg + 0] - mr);
            float p1 = __builtin_amdgcn_exp2f(sv[reg + 1] - mr);
            float p2 = __builtin_amdgcn_exp2f(sv[reg + 2] - mr);
            float p3 = __builtin_amdgcn_exp2f(sv[reg + 3] - mr);
            sv[reg + 0] = p0; sv[reg + 1] = p1;
            sv[reg + 2] = p2; sv[reg + 3] = p3;
            s0 += p0; s1 += p1; s2 += p2; s3 += p3;
        }
        float rsl = (s0 + s1) + (s2 + s3);
        float2 rp = xswap(rsl);
        float rs = rp.x + rp.y;
        lr = lr * alpha + rs;

        bf16x8 pfr[2];
        #pragma unroll
        for (int kb16 = 0; kb16 < 2; ++kb16) {
            unsigned W00 = packbf(sv[(2*kb16+0)*4 + 0], sv[(2*kb16+0)*4 + 1]);
            unsigned W01 = packbf(sv[(2*kb16+0)*4 + 2], sv[(2*kb16+0)*4 + 3]);
            unsigned W10 = packbf(sv[(2*kb16+1)*4 + 0], sv[(2*kb16+1)*4 + 1]);
            unsigned W11 = packbf(sv[(2*kb16+1)*4 + 2], sv[(2*kb16+1)*4 + 3]);
            pswap(W00, W10);
            pswap(W01, W11);
            union { unsigned w[4]; bf16x8 v; } u;
            u.w[0] = W00; u.w[1] = W01; u.w[2] = W10; u.w[3] = W11;
            pfr[kb16] = u.v;
        }

        // ---- sv update for t+1 (sfA/sfB die here; sv free after pack above)
        #pragma unroll
        for (int reg = 0; reg < 16; ++reg)
            sv[reg] = (sfA[reg] + sfB[reg]) * SCL2
                      + ml[(t + 1) * 32 + (reg >> 2) * 8 + hi * 4 + (reg & 3)];

        // ---- PV(t)
        __builtin_amdgcn_s_setprio(1);
        #pragma unroll
        for (int dblk = 0; dblk < 4; ++dblk) {
            int d = dblk * 32 + qr;
            f32x16 a = acc[dblk];
            #pragma unroll
            for (int kb16 = 0; kb16 < 2; ++kb16) {
                int s = (2 * kb16 + hi) ^ ((d >> 1) & 3);
                bf16x8 vf = *(const bf16x8*)(Vt + d * 64 + s * 16);
                a = MFMA32(vf, pfr[kb16], a);
            }
            acc[dblk] = a;
        }
        __builtin_amdgcn_s_setprio(0);

        // ---- tile end: free buf t%3, refill with t+3, ensure t+2 landed
        __builtin_amdgcn_s_barrier();
        if (t + 3 < 64) {
            STAGE(t + 3, base0);
            asm volatile("s_waitcnt vmcnt(4)" ::: "memory");
        } else {
            asm volatile("s_waitcnt vmcnt(0)" ::: "memory");
        }
        __builtin_amdgcn_s_barrier();
        base0 = baseN;
    }

    // ---- peeled tile 63: softmax + PV only
    {
        const unsigned char* Vt = sm + base0 + 8192;
        float mx[8];
        #pragma unroll
        for (int j = 0; j < 8; ++j)
            mx[j] = fmaxf(sv[2 * j], sv[2 * j + 1]);
        float m01 = fmaxf(fmaxf(fmaxf(mx[0], mx[1]), fmaxf(mx[2], mx[3])),
                          fmaxf(fmaxf(mx[4], mx[5]), fmaxf(mx[6], mx[7])));
        float2 mp = xswap(m01);
        float mt = fmaxf(mp.x, mp.y);

        float alpha = 1.f;
        int allskip = __all(mt <= mr + 8.f);
        if (!allskip) {
            float nm = fmaxf(mr, mt);
            alpha = __builtin_amdgcn_exp2f(mr - nm);
            mr = nm;
            #pragma unroll
            for (int dblk = 0; dblk < 4; ++dblk)
                #pragma unroll
                for (int reg = 0; reg < 16; ++reg)
                    acc[dblk][reg] *= alpha;
        }

        float s0 = 0.f, s1 = 0.f, s2 = 0.f, s3 = 0.f;
        #pragma unroll
        for (int reg = 0; reg < 16; reg += 4) {
            float p0 = __builtin_amdgcn_exp2f(sv[reg + 0] - mr);
            float p1 = __builtin_amdgcn_exp2f(sv[reg + 1] - mr);
            float p2 = __builtin_amdgcn_exp2f(sv[reg + 2] - mr);
            float p3 = __builtin_amdgcn_exp2f(sv[reg + 3] - mr);
            sv[reg + 0] = p0; sv[reg + 1] = p1;
            sv[reg + 2] = p2; sv[reg + 3] = p3;
            s0 += p0; s1 += p1; s2 += p2; s3 += p3;
        }
        float rsl = (s0 + s1) + (s2 + s3);
        float2 rp = xswap(rsl);
        lr = lr * alpha + rp.x + rp.y;

        bf16x8 pfr[2];
        #pragma unroll
        for (int kb16 = 0; kb16 < 2; ++kb16) {
            unsigned W00 = packbf(sv[(2*kb16+0)*4 + 0], sv[(2*kb16+0)*4 + 1]);
            unsigned W01 = packbf(sv[(2*kb16+0)*4 + 2], sv[(2*kb16+0)*4 + 3]);
            unsigned W10 = packbf(sv[(2*kb16+1)*4 + 0], sv[(2*kb16+1)*4 + 1]);
            unsigned W11 = packbf(sv[(2*kb16+1)*4 + 2], sv[(2*kb16+1)*4 + 3]);
            pswap(W00, W10);
            pswap(W01, W11);
            union { unsigned w[4]; bf16x8 v; } u;
            u.w[0] = W00; u.w[1] = W01; u.w[2] = W10; u.w[3] = W11;
            pfr[kb16] = u.v;
        }

        #pragma unroll
        for (int dblk = 0; dblk < 4; ++dblk) {
            int d = dblk * 32 + qr;
            f32x16 a = acc[dblk];
            #pragma unroll
            for (int kb16 = 0; kb16 < 2; ++kb16) {
                int s = (2 * kb16 + hi) ^ ((d >> 1) & 3);
                bf16x8 vf = *(const bf16x8*)(Vt + d * 64 + s * 16);
                a = MFMA32(vf, pfr[kb16], a);
            }
            acc[dblk] = a;
        }
    }

    // epilogue: O[qrow][d], d = dblk*32 + rg*8 + 4*hi + q4; per-lane 1/l
    float linv = 1.f / lr;
    unsigned short* orow = O + (rowQ0 + qr) * 2048 + h * 128;
    #pragma unroll
    for (int dblk = 0; dblk < 4; ++dblk)
        #pragma unroll
        for (int rg = 0; rg < 4; ++rg) {
            float v0 = acc[dblk][rg * 4 + 0] * linv;
            float v1 = acc[dblk][rg * 4 + 1] * linv;
            float v2 = acc[dblk][rg * 4 + 2] * linv;
            float v3 = acc[dblk][rg * 4 + 3] * linv;
            uint2 o;
            o.x = packbf(v0, v1);
            o.y = packbf(v2, v3);
            *(uint2*)(orow + dblk * 32 + rg * 8 + hi * 4) = o;
        }
    #undef STAGE
}

// ---------------- host launch ----------------
extern "C" void kernel_launch(void* const* d_in, const int* in_sizes, int n_in,
                              void* d_out, int out_size, void* d_ws, size_t ws_size,
                              hipStream_t stream)
{
    (void)in_sizes; (void)n_in; (void)out_size; (void)ws_size;
    const float* x    = (const float*)d_in[0];
    const float* mask = (const float*)d_in[1];
    const float* Wq   = (const float*)d_in[2];
    const float* bq   = (const float*)d_in[3];
    const float* Wk   = (const float*)d_in[4];
    const float* bk   = (const float*)d_in[5];
    const float* Wv   = (const float*)d_in[6];
    const float* bv   = (const float*)d_in[7];
    const float* Wo   = (const float*)d_in[8];
    const float* bo   = (const float*)d_in[9];
    float* out = (float*)d_out;

    char* ws = (char*)d_ws;
    //  0..16  xb (bf16 x)
    // 16..40  Wqt,Wkt,Wvt contiguous (fused QKV B matrix; Ab reuses 16.., maskl2 32..)
    // 40..48  Wot (live to the end)
    // 48..64  Qb   64..80 Kb   80..96 Vtb
    unsigned short* xb  = (unsigned short*)(ws);
    unsigned short* Wqt = (unsigned short*)(ws + (16u << 20));
    unsigned short* Wot = (unsigned short*)(ws + (40u << 20));
    unsigned short* Qb  = (unsigned short*)(ws + (48u << 20));
    unsigned short* Kb  = (unsigned short*)(ws + (64u << 20));
    unsigned short* Vtb = (unsigned short*)(ws + (80u << 20));
    unsigned short* Ab  = (unsigned short*)(ws + (16u << 20));   // dead Wqt/Wkt
    float*          mkl = (float*)(ws + (32u << 20));            // dead Wvt

    cast_f32_bf16<<<2048, 256, 0, stream>>>(x, xb, MTOT * HHH);
    transpose_cast4<<<dim3(64, 64, 4), dim3(32, 8), 0, stream>>>(Wq, Wk, Wv, Wo, Wqt);

    gemmQKV<<<768, 512, 0, stream>>>(xb, Wqt, bq, bk, bv, Qb, Kb, Vtb);

    scale_mask<<<(BB * SS) / 256, 256, 0, stream>>>(mask, mkl);   // after QKV (Wvt dead)
    attn_fwd<<<512, 256, 0, stream>>>(Qb, Kb, Vtb, mkl, Ab);

    gemmO<<<256, 512, 0, stream>>>(Ab, Wot, bo, out);
}